// Round 13
// baseline (416.177 us; speedup 1.0000x reference)
//
#include <hip/hip_runtime.h>
#include <float.h>

#define BATCH 16
#define NPTS  2048
#define NS0   256
#define NS1   128
#define KK    32
#define EPSV  1e-5f
#define MROWS 32768.0f   // BATCH*NPTS
#define M0F   131072.0f  // BATCH*NS0*KK
#define M1F   65536.0f   // BATCH*NS1*KK

// exact numpy-order squared distance: ((dx*dx + dy*dy) + dz*dz), no FMA contraction
__device__ __forceinline__ float sqdist(float ax,float ay,float az,float bx,float by,float bz){
  float dx=__fsub_rn(ax,bx), dy=__fsub_rn(ay,by), dz=__fsub_rn(az,bz);
  return __fadd_rn(__fadd_rn(__fmul_rn(dx,dx),__fmul_rn(dy,dy)),__fmul_rn(dz,dz));
}

// ---- native f32/u32 DPP ladders (cheap wave64 reduce; winner broadcast via readlane 63)
template<int CTRL,int RM>
__device__ __forceinline__ float dpp_fmax_s(float x){
  int t = __builtin_amdgcn_update_dpp((int)0xFF800000, __float_as_int(x), CTRL, RM, 0xf, false);
  return fmaxf(x, __int_as_float(t));
}
template<int CTRL,int RM>
__device__ __forceinline__ float dpp_fmin_s(float x){
  int t = __builtin_amdgcn_update_dpp(0x7F800000, __float_as_int(x), CTRL, RM, 0xf, false);
  return fminf(x, __int_as_float(t));
}
template<int CTRL,int RM>
__device__ __forceinline__ unsigned dpp_umin_s(unsigned x){
  unsigned t = (unsigned)__builtin_amdgcn_update_dpp(-1, (int)x, CTRL, RM, 0xf, false);
  return t<x ? t : x;
}
// argmax over (v,idx): max value, tie -> lowest idx (matches np.argmax first-occurrence)
__device__ __forceinline__ void wave_argmax_f32(float v, unsigned idx, float& mall, int& sel){
  float m=v;
  m=dpp_fmax_s<0x111,0xf>(m); m=dpp_fmax_s<0x112,0xf>(m); m=dpp_fmax_s<0x114,0xf>(m);
  m=dpp_fmax_s<0x118,0xf>(m); m=dpp_fmax_s<0x142,0xa>(m); m=dpp_fmax_s<0x143,0xc>(m);
  mall = __int_as_float(__builtin_amdgcn_readlane(__float_as_int(m),63));
  unsigned c = (v==mall)? idx : 0xFFFFFFFFu;
  c=dpp_umin_s<0x111,0xf>(c); c=dpp_umin_s<0x112,0xf>(c); c=dpp_umin_s<0x114,0xf>(c);
  c=dpp_umin_s<0x118,0xf>(c); c=dpp_umin_s<0x142,0xa>(c); c=dpp_umin_s<0x143,0xc>(c);
  sel = (int)(unsigned)__builtin_amdgcn_readlane((int)c,63);
}
// argmin over (v,idx): min value, tie -> lowest idx (matches stable top_k)
__device__ __forceinline__ int wave_argmin_f32(float v, unsigned idx){
  float m=v;
  m=dpp_fmin_s<0x111,0xf>(m); m=dpp_fmin_s<0x112,0xf>(m); m=dpp_fmin_s<0x114,0xf>(m);
  m=dpp_fmin_s<0x118,0xf>(m); m=dpp_fmin_s<0x142,0xa>(m); m=dpp_fmin_s<0x143,0xc>(m);
  float mall = __int_as_float(__builtin_amdgcn_readlane(__float_as_int(m),63));
  unsigned c = (v==mall)? idx : 0xFFFFFFFFu;
  c=dpp_umin_s<0x111,0xf>(c); c=dpp_umin_s<0x112,0xf>(c); c=dpp_umin_s<0x114,0xf>(c);
  c=dpp_umin_s<0x118,0xf>(c); c=dpp_umin_s<0x142,0xa>(c); c=dpp_umin_s<0x143,0xc>(c);
  return (int)(unsigned)__builtin_amdgcn_readlane((int)c,63);
}

// ================= device bodies =================

// embed1 + fused BN1 stats: 64 points per block, coalesced t1 writes, per-channel atomics.
__device__ void embed1_body(int bid, const float* __restrict__ x, const float* __restrict__ w1,
                            float* __restrict__ coords, float* __restrict__ t1,
                            float* __restrict__ acc1S, float* __restrict__ acc1Q,
                            float* ls, float* lq){
  __shared__ float w[192];
  __shared__ float xs[3][64];
  __shared__ float fin[64][65];
  int tid = threadIdx.x;
  if (tid < 192) w[tid] = w1[tid];
  if (tid < 64){ ls[tid]=0.f; lq[tid]=0.f; }
  int base = bid*64;
  int b = base / NPTS, n0 = base % NPTS;
  if (tid < 192){
    int ch = tid>>6, i = tid&63;
    xs[ch][i] = x[((size_t)b*3+ch)*NPTS + n0 + i];
  }
  __syncthreads();
  if (tid < 64){
    coords[(size_t)(base+tid)*3+0]=xs[0][tid];
    coords[(size_t)(base+tid)*3+1]=xs[1][tid];
    coords[(size_t)(base+tid)*3+2]=xs[2][tid];
  }
  int p = tid>>2, c0 = (tid&3)<<4;
  float cx=xs[0][p], cy=xs[1][p], cz=xs[2][p];
  #pragma unroll
  for(int j=0;j<16;j++){
    int c = c0+j;
    fin[p][c] = cx*w[c*3+0] + cy*w[c*3+1] + cz*w[c*3+2];
  }
  __syncthreads();
  float s=0.f,q=0.f;
  for(int i=tid;i<4096;i+=256){
    int pp=i>>6, c=i&63;          // c == tid&63, constant across iters
    float v = fin[pp][c];
    t1[(size_t)base*64 + i] = v;  // coalesced 1KB wave-stores
    s+=v; q+=v*v;
  }
  atomicAdd(&ls[tid&63], s);
  atomicAdd(&lq[tid&63], q);
  __syncthreads();
  if(tid<64){ atomicAdd(acc1S+tid, ls[tid]); atomicAdd(acc1Q+tid, lq[tid]); }
}

__device__ void wt_body(int gid, const float* __restrict__ w0, float* __restrict__ wt0,
                        const float* __restrict__ w1, float* __restrict__ wt1){
  if(gid < 128*128){
    int o = gid % 128, c = gid / 128;
    wt0[gid] = w0[o*128 + c];
  } else {
    int g2 = gid - 128*128;
    if(g2 >= 256*256) return;
    int o = g2 % 256, c = g2 / 256;
    wt1[g2] = w1[o*256 + c];
  }
}

// embed2 + fused BN2 stats: BN1 inline from sums; per-channel atomics on raw output.
__device__ void embed2_body(int bid, const float* __restrict__ t1, const float* __restrict__ w2,
                            const float* __restrict__ accS, const float* __restrict__ accQ,
                            const float* __restrict__ g1, const float* __restrict__ b1,
                            float* __restrict__ t2,
                            float* __restrict__ acc2S, float* __restrict__ acc2Q,
                            float* ls, float* lq, char* smem){
  float (*fin)[64] = (float(*)[64])smem;          // 16 KB dyn
  float* sm = (float*)smem + 4096;
  float* sr = sm+64; float* sg = sr+64; float* sb = sg+64;
  int tid = threadIdx.x;
  if (tid<64){
    float S=accS[tid], Q=accQ[tid];
    float m = S/MROWS, v = Q/MROWS - m*m; if(v<0.f) v=0.f;
    sm[tid]=m; sr[tid]=rsqrtf(v+EPSV); sg[tid]=g1[tid]; sb[tid]=b1[tid];
    ls[tid]=0.f; lq[tid]=0.f;
  }
  __syncthreads();
  int base = bid*64;
  for(int i=tid;i<4096;i+=256){
    int p=i>>6, c=i&63;
    float v = t1[(size_t)(base+p)*64 + c];
    v = (v - sm[c])*sr[c]*sg[c] + sb[c];
    fin[p][c] = v>0.f ? v : 0.f;
  }
  __syncthreads();
  int o = tid & 63, p0 = tid>>6;
  float acc[16];
  #pragma unroll
  for(int i=0;i<16;i++) acc[i]=0.f;
  for(int cc=0; cc<64; cc+=4){
    float4 wv = *(const float4*)(w2 + o*64 + cc);
    #pragma unroll
    for(int i=0;i<16;i++){
      float4 f4 = *(const float4*)&fin[p0 + i*4][cc];
      acc[i] += f4.x*wv.x + f4.y*wv.y + f4.z*wv.z + f4.w*wv.w;
    }
  }
  float s=0.f,q=0.f;
  #pragma unroll
  for(int i=0;i<16;i++){
    float v = acc[i];
    t2[(size_t)(base+p0+i*4)*64 + o] = v;
    s+=v; q+=v*v;
  }
  atomicAdd(&ls[o], s);
  atomicAdd(&lq[o], q);
  __syncthreads();
  if(tid<64){ atomicAdd(acc2S+tid, ls[tid]); atomicAdd(acc2Q+tid, lq[tid]); }
}

// multi-wave FPS v4 (FROZEN: measured 124-126us). Do not restructure.
template<int P, int S, int T>
__device__ void fps_body(int b, const float* __restrict__ x, int* __restrict__ outIdx,
                         float* __restrict__ outXyz, char* smem){
  constexpr int PPT = P/T;
  constexpr int NW  = T/64;
  float* sx=(float*)smem; float* sy=sx+P; float* sz=sy+P;
  int* sidx=(int*)(sz+P);
  unsigned long long* rv64=(unsigned long long*)(sidx+S);
  int tid = threadIdx.x;
  const float* xb = x + (size_t)b*3*P;
  float px[PPT], py[PPT], pz[PPT], dist[PPT];
  #pragma unroll
  for(int i=0;i<PPT;i++){
    int n = i*T + tid;
    float X=xb[n], Y=xb[P+n], Z=xb[2*P+n];
    px[i]=X; py[i]=Y; pz[i]=Z; dist[i]=1e10f;
    sx[n]=X; sy[n]=Y; sz[n]=Z;
  }
  __syncthreads();
  int cur = 0;
  float cx=sx[0], cy=sy[0], cz=sz[0];
  for(int s=0;s<S;s++){
    if(tid==0) sidx[s]=cur;
    if(s==S-1) break;
    float bv=-FLT_MAX; int bi=0;
    #pragma unroll
    for(int i=0;i<PPT;i++){
      float d = sqdist(px[i],py[i],pz[i],cx,cy,cz);
      float nd = fminf(dist[i], d);
      dist[i]=nd;
      int n = i*T + tid;                  // ascending per lane => '>' keeps lowest idx
      if(nd>bv){ bv=nd; bi=n; }
    }
    float mall; int sel;
    wave_argmax_f32(bv,(unsigned)bi,mall,sel);
    int sl = s & 1;
    if((tid&63)==0) rv64[sl*NW+(tid>>6)] = ((unsigned long long)__float_as_uint(mall)<<32)|(unsigned)(~sel);
    __syncthreads();
    unsigned long long wk = rv64[sl*NW];
    #pragma unroll
    for(int w=1;w<NW;w++){ unsigned long long t = rv64[sl*NW+w]; if(t>wk) wk=t; }
    cur = (int)(~(unsigned)wk);
    cx=sx[cur]; cy=sy[cur]; cz=sz[cur];
  }
  __syncthreads();
  for(int i=tid; i<S; i+=T){
    int id = sidx[i];
    outIdx[b*S+i] = id;
    outXyz[((size_t)b*S+i)*3+0] = sx[id];
    outXyz[((size_t)b*S+i)*3+1] = sy[id];
    outXyz[((size_t)b*S+i)*3+2] = sz[id];
  }
}

// single-wave FPS; float4-packed LDS points
template<int P, int S>
__device__ void fps_wave_body(int b, const float* __restrict__ pts, int* __restrict__ outIdx,
                              float* __restrict__ outXyz, char* smem){
  constexpr int PPT = P/64;
  float4* sp = (float4*)smem;
  int* sidx = (int*)(smem + P*sizeof(float4));
  int lane = threadIdx.x;
  const float* p = pts + (size_t)b*P*3;
  float px[PPT], py[PPT], pz[PPT], dist[PPT];
  #pragma unroll
  for(int i=0;i<PPT;i++){
    int n = i*64 + lane;
    float X=p[n*3], Y=p[n*3+1], Z=p[n*3+2];
    px[i]=X; py[i]=Y; pz[i]=Z; dist[i]=1e10f;
    sp[n] = make_float4(X,Y,Z,0.f);
  }
  __syncthreads();
  int cur = 0;
  float cx=sp[0].x, cy=sp[0].y, cz=sp[0].z;
  for(int s=0;s<S;s++){
    if(lane==0) sidx[s]=cur;
    if(s==S-1) break;
    float bv=-FLT_MAX; int bi=0;
    #pragma unroll
    for(int i=0;i<PPT;i++){
      float d = sqdist(px[i],py[i],pz[i],cx,cy,cz);
      float nd = fminf(dist[i], d);
      dist[i]=nd;
      int n = i*64 + lane;
      if(nd>bv){ bv=nd; bi=n; }
    }
    float mall; int sel;
    wave_argmax_f32(bv,(unsigned)bi,mall,sel);
    cur = sel;
    float4 cp = sp[cur];
    cx=cp.x; cy=cp.y; cz=cp.z;
  }
  __syncthreads();
  for(int i=lane; i<S; i+=64){
    int id = sidx[i];
    float4 cp = sp[id];
    outIdx[b*S+i] = id;
    outXyz[((size_t)b*S+i)*3+0] = cp.x;
    outXyz[((size_t)b*S+i)*3+1] = cp.y;
    outXyz[((size_t)b*S+i)*3+2] = cp.z;
  }
}

// KNN tournament: register-resident, no LDS, no barriers.
template<int P>
__device__ void knn_body(int bq, const float* __restrict__ pts, const float* __restrict__ q,
                         int S, int* __restrict__ knn){
  constexpr int E = P/64;
  int lane = threadIdx.x;
  int b = bq / S;
  const float* p = pts + (size_t)b*P*3;
  float qx=q[(size_t)bq*3], qy=q[(size_t)bq*3+1], qz=q[(size_t)bq*3+2];
  float dl[E];
  float mv = FLT_MAX; unsigned mi = 0xFFFFFFFFu;
  #pragma unroll
  for(int i=0;i<E;i++){
    int n = i*64 + lane;
    float v = sqdist(qx,qy,qz,p[n*3],p[n*3+1],p[n*3+2]);
    dl[i] = v;
    if(v<mv){ mv=v; mi=(unsigned)n; }
  }
  for(int j=0;j<KK;j++){
    int sel = wave_argmin_f32(mv, mi);
    if(lane==0) knn[(size_t)bq*KK+j] = sel;
    if((sel & 63) == lane){
      int slot = sel >> 6;
      #pragma unroll
      for(int i=0;i<E;i++) if(i==slot) dl[i]=FLT_MAX;
      mv = FLT_MAX; mi = 0xFFFFFFFFu;
      #pragma unroll
      for(int i=0;i<E;i++){
        int n=i*64+lane;
        if(dl[i]<mv){ mv=dl[i]; mi=(unsigned)n; }
      }
    }
  }
}

// register-tiled outer-product GEMM with fused input transform.
// MODE 1: BN+ReLU from raw sums (pass1a, feats=t2). MODE 2: BN-select+ReLU from
// stage-0 stats over (hmax,hmin) pair (pass1b; feats=hmax0, feats2=hmin0) — f1 never materialized.
template<int C, int P, int MODE>
__device__ void pass1_body(int bq, const float* __restrict__ feats, const float* __restrict__ feats2,
                           const int* __restrict__ knn,
                           const int* __restrict__ fpsIdx, const float* __restrict__ WT,
                           float* __restrict__ hmax, float* __restrict__ hmin,
                           float* __restrict__ part, int S,
                           const float* __restrict__ accS, const float* __restrict__ accQ,
                           const float* __restrict__ bg, const float* __restrict__ bb){
  constexpr int O   = 2*C;
  constexpr int TPB = C;
  constexpr int C4  = C/4;
  constexpr int OG  = O/8;
  constexpr int LDC = C+4;
  __shared__ __align__(16) float gfp[KK*LDC];
  __shared__ __align__(16) float cf[C];
  __shared__ __align__(16) float sa[C], sbb[C];
  __shared__ float sct[O];
  int tid = threadIdx.x;
  int b = bq / S;
  const float* fb = feats + (size_t)b*P*C;
  const float* fb2 = (MODE==2) ? feats2 + (size_t)b*P*C : nullptr;
  int ci = fpsIdx[bq];
  {
    float Mv = (MODE==1) ? MROWS : M0F;
    float S_=accS[tid], Q_=accQ[tid];
    float m = S_/Mv, vv = Q_/Mv - m*m; if(vv<0.f) vv=0.f;
    float a = rsqrtf(vv+EPSV)*bg[tid];
    float sh = bb[tid] - m*a;
    sa[tid]=a; sbb[tid]=sh;
    float raw;
    if(MODE==1) raw = fb[(size_t)ci*C + tid];
    else        raw = (a>=0.f) ? fb[(size_t)ci*C + tid] : fb2[(size_t)ci*C + tid];
    float cv = a*raw + sh;
    cf[tid] = cv>0.f ? cv : 0.f;
  }
  __syncthreads();
  for(int i=tid; i<KK*C4; i+=TPB){
    int k = i/C4, d4 = i - k*C4;
    size_t row = (size_t)knn[(size_t)bq*KK+k]*C;
    float4 a4 = *(const float4*)&sa[d4*4];
    float4 s4 = *(const float4*)&sbb[d4*4];
    float4 c4 = *(const float4*)&cf[d4*4];
    float4 g  = ((const float4*)(fb + row))[d4];
    float4 r;
    if(MODE==2){
      float4 g2 = ((const float4*)(fb2 + row))[d4];
      float gx = (a4.x>=0.f? g.x : g2.x)*a4.x + s4.x; gx = gx>0.f?gx:0.f;
      float gy = (a4.y>=0.f? g.y : g2.y)*a4.y + s4.y; gy = gy>0.f?gy:0.f;
      float gz = (a4.z>=0.f? g.z : g2.z)*a4.z + s4.z; gz = gz>0.f?gz:0.f;
      float gw = (a4.w>=0.f? g.w : g2.w)*a4.w + s4.w; gw = gw>0.f?gw:0.f;
      r.x=gx-c4.x; r.y=gy-c4.y; r.z=gz-c4.z; r.w=gw-c4.w;
    } else {
      float gx = a4.x*g.x+s4.x; gx = gx>0.f?gx:0.f;
      float gy = a4.y*g.y+s4.y; gy = gy>0.f?gy:0.f;
      float gz = a4.z*g.z+s4.z; gz = gz>0.f?gz:0.f;
      float gw = a4.w*g.w+s4.w; gw = gw>0.f?gw:0.f;
      r.x=gx-c4.x; r.y=gy-c4.y; r.z=gz-c4.z; r.w=gw-c4.w;
    }
    *(float4*)&gfp[k*LDC + d4*4] = r;
  }
  __syncthreads();
  {
    int o2 = tid*2;
    float ct0=0.f, ct1=0.f;
    for(int c=0;c<C;c+=4){
      float4 c4 = *(const float4*)&cf[c];
      #pragma unroll
      for(int t=0;t<4;t++){
        float cv = ((const float*)&c4)[t];
        float2 wh = *(const float2*)&WT[(size_t)(C+c+t)*O + o2];
        ct0 += cv*wh.x; ct1 += cv*wh.y;
      }
    }
    sct[o2]=ct0; sct[o2+1]=ct1;
  }
  __syncthreads();
  int kg = tid / OG;
  int og = tid % OG;
  float acc[8][8];
  #pragma unroll
  for(int a=0;a<8;a++)
    #pragma unroll
    for(int bb2=0;bb2<8;bb2++) acc[a][bb2]=0.f;
  for(int dc=0; dc<C4; dc++){
    float4 g4[8];
    #pragma unroll
    for(int jk=0;jk<8;jk++) g4[jk] = *(const float4*)&gfp[(kg*8+jk)*LDC + dc*4];
    #pragma unroll
    for(int t=0;t<4;t++){
      const float* wrow = WT + (size_t)(dc*4+t)*O + og*8;
      float4 wa = *(const float4*)wrow;
      float4 wb = *(const float4*)(wrow+4);
      #pragma unroll
      for(int jk=0;jk<8;jk++){
        float gs = ((const float*)&g4[jk])[t];
        acc[jk][0] += gs*wa.x; acc[jk][1] += gs*wa.y; acc[jk][2] += gs*wa.z; acc[jk][3] += gs*wa.w;
        acc[jk][4] += gs*wb.x; acc[jk][5] += gs*wb.y; acc[jk][6] += gs*wb.z; acc[jk][7] += gs*wb.w;
      }
    }
  }
  float tmx[8],tmn[8],tsm[8],tsq[8];
  #pragma unroll
  for(int jo=0;jo<8;jo++){
    int o = og*8+jo;
    float ct = sct[o];
    float s=0.f,q=0.f,mx=-FLT_MAX,mn=FLT_MAX;
    #pragma unroll
    for(int jk=0;jk<8;jk++){
      float h = acc[jk][jo] + ct;
      s+=h; q+=h*h; mx=fmaxf(mx,h); mn=fminf(mn,h);
    }
    tmx[jo]=mx; tmn[jo]=mn; tsm[jo]=s; tsq[jo]=q;
  }
  if constexpr (TPB==64){
    #pragma unroll
    for(int jo=0;jo<8;jo++){
      tmx[jo]=fmaxf(tmx[jo],__shfl_xor(tmx[jo],16)); tmx[jo]=fmaxf(tmx[jo],__shfl_xor(tmx[jo],32));
      tmn[jo]=fminf(tmn[jo],__shfl_xor(tmn[jo],16)); tmn[jo]=fminf(tmn[jo],__shfl_xor(tmn[jo],32));
      tsm[jo]+=__shfl_xor(tsm[jo],16); tsm[jo]+=__shfl_xor(tsm[jo],32);
      tsq[jo]+=__shfl_xor(tsq[jo],16); tsq[jo]+=__shfl_xor(tsq[jo],32);
    }
    if(tid<OG){
      #pragma unroll
      for(int jo=0;jo<8;jo++){
        int o = tid*8+jo;
        hmax[(size_t)bq*O+o]=tmx[jo]; hmin[(size_t)bq*O+o]=tmn[jo];
        part[(size_t)bq*2*O+o]=tsm[jo]; part[(size_t)bq*2*O+O+o]=tsq[jo];
      }
    }
  } else {
    #pragma unroll
    for(int jo=0;jo<8;jo++){
      tmx[jo]=fmaxf(tmx[jo],__shfl_xor(tmx[jo],32));
      tmn[jo]=fminf(tmn[jo],__shfl_xor(tmn[jo],32));
      tsm[jo]+=__shfl_xor(tsm[jo],32);
      tsq[jo]+=__shfl_xor(tsq[jo],32);
    }
    int wv = tid>>6;
    if((tid&63)<32){
      int og_ = tid&31;
      size_t rb = (size_t)bq*2 + wv;        // doubled row per wave; combined downstream
      #pragma unroll
      for(int jo=0;jo<8;jo++){
        int o = og_*8+jo;
        hmax[rb*O+o]=tmx[jo]; hmin[rb*O+o]=tmn[jo];
        part[rb*2*O+o]=tsm[jo]; part[rb*2*O+O+o]=tsq[jo];
      }
    }
  }
}

// ================= kernels =================

// L1: embed1+stats1 (0..511) || wt (512..831)
__global__ __launch_bounds__(256) void k_embed1_wt(const float* __restrict__ x, const float* __restrict__ w1,
                         float* __restrict__ coords, float* __restrict__ t1,
                         const float* __restrict__ wsg0, float* __restrict__ wt0,
                         const float* __restrict__ wsg1, float* __restrict__ wt1,
                         float* __restrict__ acc1S, float* __restrict__ acc1Q){
  __shared__ float ls[64], lq[64];
  if(blockIdx.x < 512) embed1_body(blockIdx.x, x, w1, coords, t1, acc1S, acc1Q, ls, lq);
  else wt_body((blockIdx.x-512)*256 + threadIdx.x, wsg0, wt0, wsg1, wt1);
}

// L3: fps0 (16 blocks) || embed2+stats2 (512 blocks); dyn smem = 25664 B (union)
__global__ __launch_bounds__(256, 1) void k_fps0_embed2(const float* __restrict__ x,
                         int* __restrict__ fps0, float* __restrict__ xyz0,
                         const float* __restrict__ t1, const float* __restrict__ w2,
                         const float* __restrict__ acc1S, const float* __restrict__ acc1Q,
                         const float* __restrict__ g1, const float* __restrict__ b1,
                         float* __restrict__ t2,
                         float* __restrict__ acc2S, float* __restrict__ acc2Q){
  extern __shared__ char smem[];
  __shared__ float ls[64], lq[64];
  if(blockIdx.x < BATCH) fps_body<NPTS,NS0,256>(blockIdx.x, x, fps0, xyz0, smem);
  else embed2_body(blockIdx.x-BATCH, t1, w2, acc1S, acc1Q, g1, b1, t2, acc2S, acc2Q, ls, lq, smem);
}

// L4: fps1 (16) || knn0 (4096, no LDS); dyn smem = 4608 B (fps1 only)
__global__ __launch_bounds__(64, 4) void k_fps1_knn0(const float* __restrict__ xyz0,
                         int* __restrict__ fps1, float* __restrict__ xyz1,
                         const float* __restrict__ coords, int* __restrict__ knn0){
  extern __shared__ char smem[];
  if(blockIdx.x < BATCH) fps_wave_body<NS0,NS1>(blockIdx.x, xyz0, fps1, fps1 ? xyz1 : xyz1, smem);
  else knn_body<NPTS>(blockIdx.x-BATCH, coords, xyz0, NS0, knn0);
}

// L5: pass1a MODE1 (4096) || knn1 (2048, no LDS)
__global__ __launch_bounds__(64, 2) void k_pass1a_knn1(const float* __restrict__ t2,
                         const int* __restrict__ knn0, const int* __restrict__ fps0,
                         const float* __restrict__ wt0,
                         float* __restrict__ hmax0, float* __restrict__ hmin0, float* __restrict__ part0,
                         const float* __restrict__ acc2S, const float* __restrict__ acc2Q,
                         const float* __restrict__ g2, const float* __restrict__ b2,
                         const float* __restrict__ xyz0, const float* __restrict__ xyz1,
                         int* __restrict__ knn1){
  if(blockIdx.x < BATCH*NS0)
    pass1_body<64,NPTS,1>(blockIdx.x, t2, nullptr, knn0, fps0, wt0, hmax0, hmin0, part0, NS0,
                          acc2S, acc2Q, g2, b2);
  else
    knn_body<NS0>(blockIdx.x-BATCH*NS0, xyz0, xyz1, NS1, knn1);
}

// L8: pass1b MODE2 — gathers straight from hmax0/hmin0, stage-0 BN+ReLU fused (no f1)
__global__ __launch_bounds__(128, 2) void k_pass1b(const float* __restrict__ hmax0,
                         const float* __restrict__ hmin0,
                         const int* __restrict__ knn1, const int* __restrict__ fps1,
                         const float* __restrict__ wt1,
                         float* __restrict__ hmax1, float* __restrict__ hmin1, float* __restrict__ part1,
                         const float* __restrict__ accB0S, const float* __restrict__ accB0Q,
                         const float* __restrict__ gsg0, const float* __restrict__ bsg0){
  pass1_body<128,NS0,2>(blockIdx.x, hmax0, hmin0, knn1, fps1, wt1, hmax1, hmin1, part1, NS1,
                        accB0S, accB0Q, gsg0, bsg0);
}

// row-coalesced partial-sum reduce: block = 64 rows; one atomic per column
__global__ __launch_bounds__(256) void k_statsB(const float* __restrict__ part, int W,
                                                float* __restrict__ acc){
  int tid = threadIdx.x;
  int r0 = blockIdx.x*64;
  for(int c=tid; c<W; c+=256){
    float a=0.f;
    for(int r=0;r<64;r++) a += part[(size_t)(r0+r)*W + c];
    atomicAdd(acc+c, a);
  }
}

// stage-1 postmax + transpose via LDS tile; combines the doubled stat rows.
__global__ __launch_bounds__(256) void k_post1tr(const float* __restrict__ hmax, const float* __restrict__ hmin,
        const float* __restrict__ aS, const float* __restrict__ aQ,
        const float* __restrict__ g, const float* __restrict__ bb, float* __restrict__ out){
  __shared__ float ssc[64], ssh[64];
  __shared__ float tile[64][129];
  int tid = threadIdx.x;
  int blk = blockIdx.x; int b = blk>>2; int c0 = (blk&3)*64;
  if(tid<64){
    int o = c0+tid;
    float m = aS[o]/M1F, v = aQ[o]/M1F - m*m; if(v<0.f) v=0.f;
    float sc = rsqrtf(v+EPSV)*g[o];
    ssc[tid]=sc; ssh[tid]=bb[o]-m*sc;
  }
  __syncthreads();
  for(int i=tid; i<128*64; i+=256){
    int r=i>>6, ch=i&63;
    size_t rb = (size_t)(b*NS1+r)*2;
    float sc = ssc[ch];
    float va = hmax[rb*256 + c0+ch], vb = hmax[(rb+1)*256 + c0+ch];
    float wa = hmin[rb*256 + c0+ch], wb = hmin[(rb+1)*256 + c0+ch];
    float h = (sc>=0.f) ? fmaxf(va,vb) : fminf(wa,wb);
    float v = h*sc + ssh[ch];
    tile[ch][r] = v>0.f ? v : 0.f;
  }
  __syncthreads();
  for(int i=tid; i<64*128; i+=256){
    int ch=i>>7, s=i&127;
    out[(size_t)b*(256*NS1) + (size_t)(c0+ch)*NS1 + s] = tile[ch][s];
  }
}

extern "C" void kernel_launch(void* const* d_in, const int* in_sizes, int n_in,
                              void* d_out, int out_size, void* d_ws, size_t ws_size,
                              hipStream_t stream){
  const float* x    = (const float*)d_in[0];
  const float* w1   = (const float*)d_in[1];
  const float* g1   = (const float*)d_in[2];
  const float* b1   = (const float*)d_in[3];
  const float* w2   = (const float*)d_in[4];
  const float* g2   = (const float*)d_in[5];
  const float* b2   = (const float*)d_in[6];
  const float* wsg0 = (const float*)d_in[7];
  const float* gsg0 = (const float*)d_in[8];
  const float* bsg0 = (const float*)d_in[9];
  const float* wsg1 = (const float*)d_in[10];
  const float* gsg1 = (const float*)d_in[11];
  const float* bsg1 = (const float*)d_in[12];
  float* out = (float*)d_out;

  float* wsf = (float*)d_ws;
  float* coords = wsf;                    wsf += BATCH*NPTS*3;
  float* t1     = wsf;                    wsf += BATCH*NPTS*64;   // ALIASED: part1 after L3
  float* t2     = wsf;                    wsf += BATCH*NPTS*64;   // ALIASED: hmax1|hmin1 after L5
  float* acc1S=wsf; wsf+=64;  float* acc1Q=wsf; wsf+=64;          // contiguous 1024-float accum block
  float* acc2S=wsf; wsf+=64;  float* acc2Q=wsf; wsf+=64;
  float* accB0=wsf; wsf+=256;                                      // [S x128][Q x128]
  float* accB1=wsf; wsf+=512;                                      // [S x256][Q x256]
  int*   fps0 = (int*)wsf;                wsf += BATCH*NS0;
  float* xyz0 = wsf;                      wsf += BATCH*NS0*3;
  int*   knn0 = (int*)wsf;                wsf += BATCH*NS0*KK;
  float* hmax0= wsf;                      wsf += BATCH*NS0*128;
  float* hmin0= wsf;                      wsf += BATCH*NS0*128;
  float* part0= wsf;                      wsf += BATCH*NS0*2*128;
  int*   fps1 = (int*)wsf;                wsf += BATCH*NS1;
  float* xyz1 = wsf;                      wsf += BATCH*NS1*3;
  int*   knn1 = (int*)wsf;                wsf += BATCH*NS1*KK;
  float* wt0  = wsf;                      wsf += 128*128;
  float* wt1  = wsf;                      wsf += 256*256;
  // aliases (t1 dead after L3; t2 dead after L5)
  float* part1 = t1;                      // (NB1*2) x 512 = 2,097,152 floats == |t1|
  float* hmax1 = t2;                      // (NB1*2) x 256
  float* hmin1 = t2 + BATCH*NS1*2*256;

  const int DYN_L3 = (NPTS*3 + NS0)*4 + 2*4*8;     // fps0 union (>= embed2 17408)
  const int DYN_L4 = NS0*16 + NS1*4;               // fps1 float4 sp + sidx = 4608

  // L0: zero all stats accumulators (4 KB) — graph-capture-safe
  hipMemsetAsync(acc1S, 0, 1024*sizeof(float), stream);
  // L1: embed1 + fused BN1 stats || weight transposes
  k_embed1_wt<<<dim3(832), dim3(256), 0, stream>>>(x, w1, coords, t1, wsg0, wt0, wsg1, wt1,
                                                   acc1S, acc1Q);
  // L3: fps0 (FROZEN v4) || embed2 + fused BN2 stats
  k_fps0_embed2<<<dim3(BATCH+512), dim3(256), DYN_L3, stream>>>(x, fps0, xyz0,
                                                  t1, w2, acc1S, acc1Q, g1, b1, t2, acc2S, acc2Q);
  // L4: fps1 || knn0 (tournament)
  k_fps1_knn0<<<dim3(BATCH + BATCH*NS0), dim3(64), DYN_L4, stream>>>(xyz0, fps1, xyz1, coords, knn0);
  // L5: pass1a (BN2 fused) || knn1 (tournament)
  k_pass1a_knn1<<<dim3(BATCH*NS0 + BATCH*NS1), dim3(64), 0, stream>>>(t2, knn0, fps0, wt0,
                                                  hmax0, hmin0, part0,
                                                  acc2S, acc2Q, g2, b2,
                                                  xyz0, xyz1, knn1);
  // L6: reduce part0 -> accB0
  k_statsB<<<dim3(64), dim3(256), 0, stream>>>(part0, 256, accB0);
  // L8: pass1b (BN0-select fused; f1 never materialized)
  k_pass1b<<<dim3(BATCH*NS1), dim3(128), 0, stream>>>(hmax0, hmin0, knn1, fps1, wt1,
                                                  hmax1, hmin1, part1,
                                                  accB0, accB0+128, gsg0, bsg0);
  // L9: reduce part1 -> accB1
  k_statsB<<<dim3(64), dim3(256), 0, stream>>>(part1, 512, accB1);
  // L10: postmax + transpose -> out
  k_post1tr<<<dim3(64), dim3(256), 0, stream>>>(hmax1, hmin1, accB1, accB1+256, gsg1, bsg1, out);
}

// Round 14
// 402.409 us; speedup vs baseline: 1.0342x; 1.0342x over previous
//
#include <hip/hip_runtime.h>
#include <float.h>

#define BATCH 16
#define NPTS  2048
#define NS0   256
#define NS1   128
#define KK    32
#define EPSV  1e-5f
#define MROWS 32768.0f   // BATCH*NPTS
#define M0F   131072.0f  // BATCH*NS0*KK
#define M1F   65536.0f   // BATCH*NS1*KK

// exact numpy-order squared distance: ((dx*dx + dy*dy) + dz*dz), no FMA contraction
__device__ __forceinline__ float sqdist(float ax,float ay,float az,float bx,float by,float bz){
  float dx=__fsub_rn(ax,bx), dy=__fsub_rn(ay,by), dz=__fsub_rn(az,bz);
  return __fadd_rn(__fadd_rn(__fmul_rn(dx,dx),__fmul_rn(dy,dy)),__fmul_rn(dz,dz));
}

// ---- native f32/u32 DPP ladders (cheap wave64 reduce; winner broadcast via readlane 63)
template<int CTRL,int RM>
__device__ __forceinline__ float dpp_fmax_s(float x){
  int t = __builtin_amdgcn_update_dpp((int)0xFF800000, __float_as_int(x), CTRL, RM, 0xf, false);
  return fmaxf(x, __int_as_float(t));
}
template<int CTRL,int RM>
__device__ __forceinline__ float dpp_fmin_s(float x){
  int t = __builtin_amdgcn_update_dpp(0x7F800000, __float_as_int(x), CTRL, RM, 0xf, false);
  return fminf(x, __int_as_float(t));
}
template<int CTRL,int RM>
__device__ __forceinline__ unsigned dpp_umin_s(unsigned x){
  unsigned t = (unsigned)__builtin_amdgcn_update_dpp(-1, (int)x, CTRL, RM, 0xf, false);
  return t<x ? t : x;
}
// argmax over (v,idx): max value, tie -> lowest idx (matches np.argmax first-occurrence)
__device__ __forceinline__ void wave_argmax_f32(float v, unsigned idx, float& mall, int& sel){
  float m=v;
  m=dpp_fmax_s<0x111,0xf>(m); m=dpp_fmax_s<0x112,0xf>(m); m=dpp_fmax_s<0x114,0xf>(m);
  m=dpp_fmax_s<0x118,0xf>(m); m=dpp_fmax_s<0x142,0xa>(m); m=dpp_fmax_s<0x143,0xc>(m);
  mall = __int_as_float(__builtin_amdgcn_readlane(__float_as_int(m),63));
  unsigned c = (v==mall)? idx : 0xFFFFFFFFu;
  c=dpp_umin_s<0x111,0xf>(c); c=dpp_umin_s<0x112,0xf>(c); c=dpp_umin_s<0x114,0xf>(c);
  c=dpp_umin_s<0x118,0xf>(c); c=dpp_umin_s<0x142,0xa>(c); c=dpp_umin_s<0x143,0xc>(c);
  sel = (int)(unsigned)__builtin_amdgcn_readlane((int)c,63);
}
// argmin over (v,idx): min value, tie -> lowest idx (matches stable top_k)
__device__ __forceinline__ int wave_argmin_f32(float v, unsigned idx){
  float m=v;
  m=dpp_fmin_s<0x111,0xf>(m); m=dpp_fmin_s<0x112,0xf>(m); m=dpp_fmin_s<0x114,0xf>(m);
  m=dpp_fmin_s<0x118,0xf>(m); m=dpp_fmin_s<0x142,0xa>(m); m=dpp_fmin_s<0x143,0xc>(m);
  float mall = __int_as_float(__builtin_amdgcn_readlane(__float_as_int(m),63));
  unsigned c = (v==mall)? idx : 0xFFFFFFFFu;
  c=dpp_umin_s<0x111,0xf>(c); c=dpp_umin_s<0x112,0xf>(c); c=dpp_umin_s<0x114,0xf>(c);
  c=dpp_umin_s<0x118,0xf>(c); c=dpp_umin_s<0x142,0xa>(c); c=dpp_umin_s<0x143,0xc>(c);
  return (int)(unsigned)__builtin_amdgcn_readlane((int)c,63);
}

// ================= device bodies =================

// embed1 v2 (r12-proven): 64 points/block, LDS-staged coalesced t1 writes. No stats fusion.
__device__ void embed1_body(int bid, const float* __restrict__ x, const float* __restrict__ w1,
                            float* __restrict__ coords, float* __restrict__ t1){
  __shared__ float w[192];
  __shared__ float xs[3][64];
  __shared__ float fin[64][65];
  int tid = threadIdx.x;
  if (tid < 192) w[tid] = w1[tid];
  int base = bid*64;
  int b = base / NPTS, n0 = base % NPTS;
  if (tid < 192){
    int ch = tid>>6, i = tid&63;
    xs[ch][i] = x[((size_t)b*3+ch)*NPTS + n0 + i];
  }
  __syncthreads();
  if (tid < 64){
    coords[(size_t)(base+tid)*3+0]=xs[0][tid];
    coords[(size_t)(base+tid)*3+1]=xs[1][tid];
    coords[(size_t)(base+tid)*3+2]=xs[2][tid];
  }
  int p = tid>>2, c0 = (tid&3)<<4;
  float cx=xs[0][p], cy=xs[1][p], cz=xs[2][p];
  #pragma unroll
  for(int j=0;j<16;j++){
    int c = c0+j;
    fin[p][c] = cx*w[c*3+0] + cy*w[c*3+1] + cz*w[c*3+2];
  }
  __syncthreads();
  for(int i=tid;i<4096;i+=256){
    int pp=i>>6, c=i&63;
    t1[(size_t)base*64 + i] = fin[pp][c];     // coalesced 1KB wave-stores
  }
}

__device__ void wt_body(int gid, const float* __restrict__ w0, float* __restrict__ wt0,
                        const float* __restrict__ w1, float* __restrict__ wt1){
  if(gid < 128*128){
    int o = gid % 128, c = gid / 128;
    wt0[gid] = w0[o*128 + c];
  } else {
    int g2 = gid - 128*128;
    if(g2 >= 256*256) return;
    int o = g2 % 256, c = g2 / 256;
    wt1[g2] = w1[o*256 + c];
  }
}

// coalesced per-block channel sums + one atomic per channel per block (64 thr)
__device__ void statsA_body(int blk, const float* __restrict__ t,
                            float* __restrict__ accS, float* __restrict__ accQ){
  int c = threadIdx.x;            // channel 0..63
  int r0 = blk*128;
  float s=0.f, q=0.f;
  for(int r=0;r<128;r++){
    float v = t[(size_t)(r0+r)*64 + c];   // wave-load = one contiguous 256B row
    s+=v; q+=v*v;
  }
  atomicAdd(accS+c, s);
  atomicAdd(accQ+c, q);
}

// embed2 + fused BN2 stats (hidden under fps0 — free): BN1 inline from sums.
__device__ void embed2_body(int bid, const float* __restrict__ t1, const float* __restrict__ w2,
                            const float* __restrict__ accS, const float* __restrict__ accQ,
                            const float* __restrict__ g1, const float* __restrict__ b1,
                            float* __restrict__ t2,
                            float* __restrict__ acc2S, float* __restrict__ acc2Q,
                            float* ls, float* lq, char* smem){
  float (*fin)[64] = (float(*)[64])smem;          // 16 KB dyn
  float* sm = (float*)smem + 4096;
  float* sr = sm+64; float* sg = sr+64; float* sb = sg+64;
  int tid = threadIdx.x;
  if (tid<64){
    float S=accS[tid], Q=accQ[tid];
    float m = S/MROWS, v = Q/MROWS - m*m; if(v<0.f) v=0.f;
    sm[tid]=m; sr[tid]=rsqrtf(v+EPSV); sg[tid]=g1[tid]; sb[tid]=b1[tid];
    ls[tid]=0.f; lq[tid]=0.f;
  }
  __syncthreads();
  int base = bid*64;
  for(int i=tid;i<4096;i+=256){
    int p=i>>6, c=i&63;
    float v = t1[(size_t)(base+p)*64 + c];
    v = (v - sm[c])*sr[c]*sg[c] + sb[c];
    fin[p][c] = v>0.f ? v : 0.f;
  }
  __syncthreads();
  int o = tid & 63, p0 = tid>>6;
  float acc[16];
  #pragma unroll
  for(int i=0;i<16;i++) acc[i]=0.f;
  for(int cc=0; cc<64; cc+=4){
    float4 wv = *(const float4*)(w2 + o*64 + cc);
    #pragma unroll
    for(int i=0;i<16;i++){
      float4 f4 = *(const float4*)&fin[p0 + i*4][cc];
      acc[i] += f4.x*wv.x + f4.y*wv.y + f4.z*wv.z + f4.w*wv.w;
    }
  }
  float s=0.f,q=0.f;
  #pragma unroll
  for(int i=0;i<16;i++){
    float v = acc[i];
    t2[(size_t)(base+p0+i*4)*64 + o] = v;
    s+=v; q+=v*v;
  }
  atomicAdd(&ls[o], s);
  atomicAdd(&lq[o], q);
  __syncthreads();
  if(tid<64){ atomicAdd(acc2S+tid, ls[tid]); atomicAdd(acc2Q+tid, lq[tid]); }
}

// multi-wave FPS v4 (FROZEN: measured 124-127us). Do not restructure.
template<int P, int S, int T>
__device__ void fps_body(int b, const float* __restrict__ x, int* __restrict__ outIdx,
                         float* __restrict__ outXyz, char* smem){
  constexpr int PPT = P/T;
  constexpr int NW  = T/64;
  float* sx=(float*)smem; float* sy=sx+P; float* sz=sy+P;
  int* sidx=(int*)(sz+P);
  unsigned long long* rv64=(unsigned long long*)(sidx+S);
  int tid = threadIdx.x;
  const float* xb = x + (size_t)b*3*P;
  float px[PPT], py[PPT], pz[PPT], dist[PPT];
  #pragma unroll
  for(int i=0;i<PPT;i++){
    int n = i*T + tid;
    float X=xb[n], Y=xb[P+n], Z=xb[2*P+n];
    px[i]=X; py[i]=Y; pz[i]=Z; dist[i]=1e10f;
    sx[n]=X; sy[n]=Y; sz[n]=Z;
  }
  __syncthreads();
  int cur = 0;
  float cx=sx[0], cy=sy[0], cz=sz[0];
  for(int s=0;s<S;s++){
    if(tid==0) sidx[s]=cur;
    if(s==S-1) break;
    float bv=-FLT_MAX; int bi=0;
    #pragma unroll
    for(int i=0;i<PPT;i++){
      float d = sqdist(px[i],py[i],pz[i],cx,cy,cz);
      float nd = fminf(dist[i], d);
      dist[i]=nd;
      int n = i*T + tid;                  // ascending per lane => '>' keeps lowest idx
      if(nd>bv){ bv=nd; bi=n; }
    }
    float mall; int sel;
    wave_argmax_f32(bv,(unsigned)bi,mall,sel);
    int sl = s & 1;
    if((tid&63)==0) rv64[sl*NW+(tid>>6)] = ((unsigned long long)__float_as_uint(mall)<<32)|(unsigned)(~sel);
    __syncthreads();
    unsigned long long wk = rv64[sl*NW];
    #pragma unroll
    for(int w=1;w<NW;w++){ unsigned long long t = rv64[sl*NW+w]; if(t>wk) wk=t; }
    cur = (int)(~(unsigned)wk);
    cx=sx[cur]; cy=sy[cur]; cz=sz[cur];
  }
  __syncthreads();
  for(int i=tid; i<S; i+=T){
    int id = sidx[i];
    outIdx[b*S+i] = id;
    outXyz[((size_t)b*S+i)*3+0] = sx[id];
    outXyz[((size_t)b*S+i)*3+1] = sy[id];
    outXyz[((size_t)b*S+i)*3+2] = sz[id];
  }
}

// single-wave FPS; float4-packed LDS points
template<int P, int S>
__device__ void fps_wave_body(int b, const float* __restrict__ pts, int* __restrict__ outIdx,
                              float* __restrict__ outXyz, char* smem){
  constexpr int PPT = P/64;
  float4* sp = (float4*)smem;
  int* sidx = (int*)(smem + P*sizeof(float4));
  int lane = threadIdx.x;
  const float* p = pts + (size_t)b*P*3;
  float px[PPT], py[PPT], pz[PPT], dist[PPT];
  #pragma unroll
  for(int i=0;i<PPT;i++){
    int n = i*64 + lane;
    float X=p[n*3], Y=p[n*3+1], Z=p[n*3+2];
    px[i]=X; py[i]=Y; pz[i]=Z; dist[i]=1e10f;
    sp[n] = make_float4(X,Y,Z,0.f);
  }
  __syncthreads();
  int cur = 0;
  float cx=sp[0].x, cy=sp[0].y, cz=sp[0].z;
  for(int s=0;s<S;s++){
    if(lane==0) sidx[s]=cur;
    if(s==S-1) break;
    float bv=-FLT_MAX; int bi=0;
    #pragma unroll
    for(int i=0;i<PPT;i++){
      float d = sqdist(px[i],py[i],pz[i],cx,cy,cz);
      float nd = fminf(dist[i], d);
      dist[i]=nd;
      int n = i*64 + lane;
      if(nd>bv){ bv=nd; bi=n; }
    }
    float mall; int sel;
    wave_argmax_f32(bv,(unsigned)bi,mall,sel);
    cur = sel;
    float4 cp = sp[cur];
    cx=cp.x; cy=cp.y; cz=cp.z;
  }
  __syncthreads();
  for(int i=lane; i<S; i+=64){
    int id = sidx[i];
    float4 cp = sp[id];
    outIdx[b*S+i] = id;
    outXyz[((size_t)b*S+i)*3+0] = cp.x;
    outXyz[((size_t)b*S+i)*3+1] = cp.y;
    outXyz[((size_t)b*S+i)*3+2] = cp.z;
  }
}

// KNN tournament v2: per-lane top-2 cache (b1,b2) + consumed bitmask.
// b1 is always the lane's true min over unconsumed elements (elements only leave a lane
// when that lane is the global winner), so selection is bit-identical to full rescan.
// Full rescan only when both cached entries are consumed (~KK^2/(2*64) times per query).
template<int P>
__device__ void knn_body(int bq, const float* __restrict__ pts, const float* __restrict__ q,
                         int S, int* __restrict__ knn){
  constexpr int E = P/64;
  int lane = threadIdx.x;
  int b = bq / S;
  const float* p = pts + (size_t)b*P*3;
  float qx=q[(size_t)bq*3], qy=q[(size_t)bq*3+1], qz=q[(size_t)bq*3+2];
  float dl[E];
  float b1=FLT_MAX, b2=FLT_MAX;
  unsigned i1=0xFFFFFFFFu, i2=0xFFFFFFFFu, consumed=0u;
  #pragma unroll
  for(int i=0;i<E;i++){
    unsigned n = i*64 + lane;
    float v = sqdist(qx,qy,qz,p[n*3],p[n*3+1],p[n*3+2]);
    dl[i] = v;
    bool lt1 = v<b1, lt2 = v<b2;          // strict < : earliest index wins lane-local ties
    float    nb2 = lt1 ? b1 : (lt2 ? v : b2);
    unsigned ni2 = lt1 ? i1 : (lt2 ? n : i2);
    b1 = lt1 ? v : b1; i1 = lt1 ? n : i1;
    b2 = nb2; i2 = ni2;
  }
  for(int j=0;j<KK;j++){
    int sel = wave_argmin_f32(b1, i1);
    if(lane==0) knn[(size_t)bq*KK+j] = sel;
    if((sel & 63) == lane){               // owner: consume + promote; rescan only if dry
      consumed |= 1u << (sel >> 6);
      b1 = b2; i1 = i2;
      b2 = FLT_MAX; i2 = 0xFFFFFFFFu;
      if(b1 == FLT_MAX){
        #pragma unroll
        for(int i=0;i<E;i++){
          float v = ((consumed>>i)&1u) ? FLT_MAX : dl[i];
          unsigned n = i*64 + lane;
          bool lt1 = v<b1, lt2 = v<b2;
          float    nb2 = lt1 ? b1 : (lt2 ? v : b2);
          unsigned ni2 = lt1 ? i1 : (lt2 ? n : i2);
          b1 = lt1 ? v : b1; i1 = lt1 ? n : i1;
          b2 = nb2; i2 = ni2;
        }
      }
    }
  }
}

// register-tiled outer-product GEMM with fused input transform.
// MODE 1: BN+ReLU from raw sums (pass1a, feats=t2). MODE 2: BN-select+ReLU from
// stage-0 stats over (hmax,hmin) pair (pass1b) — f1 never materialized.
template<int C, int P, int MODE>
__device__ void pass1_body(int bq, const float* __restrict__ feats, const float* __restrict__ feats2,
                           const int* __restrict__ knn,
                           const int* __restrict__ fpsIdx, const float* __restrict__ WT,
                           float* __restrict__ hmax, float* __restrict__ hmin,
                           float* __restrict__ part, int S,
                           const float* __restrict__ accS, const float* __restrict__ accQ,
                           const float* __restrict__ bg, const float* __restrict__ bb){
  constexpr int O   = 2*C;
  constexpr int TPB = C;
  constexpr int C4  = C/4;
  constexpr int OG  = O/8;
  constexpr int LDC = C+4;
  __shared__ __align__(16) float gfp[KK*LDC];
  __shared__ __align__(16) float cf[C];
  __shared__ __align__(16) float sa[C], sbb[C];
  __shared__ float sct[O];
  int tid = threadIdx.x;
  int b = bq / S;
  const float* fb = feats + (size_t)b*P*C;
  const float* fb2 = (MODE==2) ? feats2 + (size_t)b*P*C : nullptr;
  int ci = fpsIdx[bq];
  {
    float Mv = (MODE==1) ? MROWS : M0F;
    float S_=accS[tid], Q_=accQ[tid];
    float m = S_/Mv, vv = Q_/Mv - m*m; if(vv<0.f) vv=0.f;
    float a = rsqrtf(vv+EPSV)*bg[tid];
    float sh = bb[tid] - m*a;
    sa[tid]=a; sbb[tid]=sh;
    float raw;
    if(MODE==1) raw = fb[(size_t)ci*C + tid];
    else        raw = (a>=0.f) ? fb[(size_t)ci*C + tid] : fb2[(size_t)ci*C + tid];
    float cv = a*raw + sh;
    cf[tid] = cv>0.f ? cv : 0.f;
  }
  __syncthreads();
  for(int i=tid; i<KK*C4; i+=TPB){
    int k = i/C4, d4 = i - k*C4;
    size_t row = (size_t)knn[(size_t)bq*KK+k]*C;
    float4 a4 = *(const float4*)&sa[d4*4];
    float4 s4 = *(const float4*)&sbb[d4*4];
    float4 c4 = *(const float4*)&cf[d4*4];
    float4 g  = ((const float4*)(fb + row))[d4];
    float4 r;
    if(MODE==2){
      float4 g2 = ((const float4*)(fb2 + row))[d4];
      float gx = (a4.x>=0.f? g.x : g2.x)*a4.x + s4.x; gx = gx>0.f?gx:0.f;
      float gy = (a4.y>=0.f? g.y : g2.y)*a4.y + s4.y; gy = gy>0.f?gy:0.f;
      float gz = (a4.z>=0.f? g.z : g2.z)*a4.z + s4.z; gz = gz>0.f?gz:0.f;
      float gw = (a4.w>=0.f? g.w : g2.w)*a4.w + s4.w; gw = gw>0.f?gw:0.f;
      r.x=gx-c4.x; r.y=gy-c4.y; r.z=gz-c4.z; r.w=gw-c4.w;
    } else {
      float gx = a4.x*g.x+s4.x; gx = gx>0.f?gx:0.f;
      float gy = a4.y*g.y+s4.y; gy = gy>0.f?gy:0.f;
      float gz = a4.z*g.z+s4.z; gz = gz>0.f?gz:0.f;
      float gw = a4.w*g.w+s4.w; gw = gw>0.f?gw:0.f;
      r.x=gx-c4.x; r.y=gy-c4.y; r.z=gz-c4.z; r.w=gw-c4.w;
    }
    *(float4*)&gfp[k*LDC + d4*4] = r;
  }
  __syncthreads();
  {
    int o2 = tid*2;
    float ct0=0.f, ct1=0.f;
    for(int c=0;c<C;c+=4){
      float4 c4 = *(const float4*)&cf[c];
      #pragma unroll
      for(int t=0;t<4;t++){
        float cv = ((const float*)&c4)[t];
        float2 wh = *(const float2*)&WT[(size_t)(C+c+t)*O + o2];
        ct0 += cv*wh.x; ct1 += cv*wh.y;
      }
    }
    sct[o2]=ct0; sct[o2+1]=ct1;
  }
  __syncthreads();
  int kg = tid / OG;
  int og = tid % OG;
  float acc[8][8];
  #pragma unroll
  for(int a=0;a<8;a++)
    #pragma unroll
    for(int bb2=0;bb2<8;bb2++) acc[a][bb2]=0.f;
  for(int dc=0; dc<C4; dc++){
    float4 g4[8];
    #pragma unroll
    for(int jk=0;jk<8;jk++) g4[jk] = *(const float4*)&gfp[(kg*8+jk)*LDC + dc*4];
    #pragma unroll
    for(int t=0;t<4;t++){
      const float* wrow = WT + (size_t)(dc*4+t)*O + og*8;
      float4 wa = *(const float4*)wrow;
      float4 wb = *(const float4*)(wrow+4);
      #pragma unroll
      for(int jk=0;jk<8;jk++){
        float gs = ((const float*)&g4[jk])[t];
        acc[jk][0] += gs*wa.x; acc[jk][1] += gs*wa.y; acc[jk][2] += gs*wa.z; acc[jk][3] += gs*wa.w;
        acc[jk][4] += gs*wb.x; acc[jk][5] += gs*wb.y; acc[jk][6] += gs*wb.z; acc[jk][7] += gs*wb.w;
      }
    }
  }
  float tmx[8],tmn[8],tsm[8],tsq[8];
  #pragma unroll
  for(int jo=0;jo<8;jo++){
    int o = og*8+jo;
    float ct = sct[o];
    float s=0.f,q=0.f,mx=-FLT_MAX,mn=FLT_MAX;
    #pragma unroll
    for(int jk=0;jk<8;jk++){
      float h = acc[jk][jo] + ct;
      s+=h; q+=h*h; mx=fmaxf(mx,h); mn=fminf(mn,h);
    }
    tmx[jo]=mx; tmn[jo]=mn; tsm[jo]=s; tsq[jo]=q;
  }
  if constexpr (TPB==64){
    #pragma unroll
    for(int jo=0;jo<8;jo++){
      tmx[jo]=fmaxf(tmx[jo],__shfl_xor(tmx[jo],16)); tmx[jo]=fmaxf(tmx[jo],__shfl_xor(tmx[jo],32));
      tmn[jo]=fminf(tmn[jo],__shfl_xor(tmn[jo],16)); tmn[jo]=fminf(tmn[jo],__shfl_xor(tmn[jo],32));
      tsm[jo]+=__shfl_xor(tsm[jo],16); tsm[jo]+=__shfl_xor(tsm[jo],32);
      tsq[jo]+=__shfl_xor(tsq[jo],16); tsq[jo]+=__shfl_xor(tsq[jo],32);
    }
    if(tid<OG){
      #pragma unroll
      for(int jo=0;jo<8;jo++){
        int o = tid*8+jo;
        hmax[(size_t)bq*O+o]=tmx[jo]; hmin[(size_t)bq*O+o]=tmn[jo];
        part[(size_t)bq*2*O+o]=tsm[jo]; part[(size_t)bq*2*O+O+o]=tsq[jo];
      }
    }
  } else {
    #pragma unroll
    for(int jo=0;jo<8;jo++){
      tmx[jo]=fmaxf(tmx[jo],__shfl_xor(tmx[jo],32));
      tmn[jo]=fminf(tmn[jo],__shfl_xor(tmn[jo],32));
      tsm[jo]+=__shfl_xor(tsm[jo],32);
      tsq[jo]+=__shfl_xor(tsq[jo],32);
    }
    int wv = tid>>6;
    if((tid&63)<32){
      int og_ = tid&31;
      size_t rb = (size_t)bq*2 + wv;        // doubled row per wave; combined downstream
      #pragma unroll
      for(int jo=0;jo<8;jo++){
        int o = og_*8+jo;
        hmax[rb*O+o]=tmx[jo]; hmin[rb*O+o]=tmn[jo];
        part[rb*2*O+o]=tsm[jo]; part[rb*2*O+O+o]=tsq[jo];
      }
    }
  }
}

// ================= kernels =================

// L1: embed1 (0..511) || wt (512..831) || zero 1024 accum floats (832)
__global__ __launch_bounds__(256) void k_embed1_wt(const float* __restrict__ x, const float* __restrict__ w1,
                         float* __restrict__ coords, float* __restrict__ t1,
                         const float* __restrict__ wsg0, float* __restrict__ wt0,
                         const float* __restrict__ wsg1, float* __restrict__ wt1,
                         float* __restrict__ accz){
  if(blockIdx.x < 512) embed1_body(blockIdx.x, x, w1, coords, t1);
  else if(blockIdx.x < 832) wt_body((blockIdx.x-512)*256 + threadIdx.x, wsg0, wt0, wsg1, wt1);
  else {
    int tid = threadIdx.x;
    accz[tid]=0.f; accz[tid+256]=0.f; accz[tid+512]=0.f; accz[tid+768]=0.f;
  }
}

// L2: BN1 stats (coalesced + atomic)
__global__ __launch_bounds__(64) void k_statsA(const float* __restrict__ t,
                         float* __restrict__ accS, float* __restrict__ accQ){
  statsA_body(blockIdx.x, t, accS, accQ);
}

// L3: fps0 (16 blocks) || embed2+stats2 (512 blocks); dyn smem = 25664 B (union)
__global__ __launch_bounds__(256, 1) void k_fps0_embed2(const float* __restrict__ x,
                         int* __restrict__ fps0, float* __restrict__ xyz0,
                         const float* __restrict__ t1, const float* __restrict__ w2,
                         const float* __restrict__ acc1S, const float* __restrict__ acc1Q,
                         const float* __restrict__ g1, const float* __restrict__ b1,
                         float* __restrict__ t2,
                         float* __restrict__ acc2S, float* __restrict__ acc2Q){
  extern __shared__ char smem[];
  __shared__ float ls[64], lq[64];
  if(blockIdx.x < BATCH) fps_body<NPTS,NS0,256>(blockIdx.x, x, fps0, xyz0, smem);
  else embed2_body(blockIdx.x-BATCH, t1, w2, acc1S, acc1Q, g1, b1, t2, acc2S, acc2Q, ls, lq, smem);
}

// L4: fps1 (16) || knn0-v2 (4096); dyn smem = 4608 B (fps1 only)
__global__ __launch_bounds__(64, 4) void k_fps1_knn0(const float* __restrict__ xyz0,
                         int* __restrict__ fps1, float* __restrict__ xyz1,
                         const float* __restrict__ coords, int* __restrict__ knn0){
  extern __shared__ char smem[];
  if(blockIdx.x < BATCH) fps_wave_body<NS0,NS1>(blockIdx.x, xyz0, fps1, xyz1, smem);
  else knn_body<NPTS>(blockIdx.x-BATCH, coords, xyz0, NS0, knn0);
}

// L5: pass1a MODE1 (4096) || knn1-v2 (2048)
__global__ __launch_bounds__(64, 2) void k_pass1a_knn1(const float* __restrict__ t2,
                         const int* __restrict__ knn0, const int* __restrict__ fps0,
                         const float* __restrict__ wt0,
                         float* __restrict__ hmax0, float* __restrict__ hmin0, float* __restrict__ part0,
                         const float* __restrict__ acc2S, const float* __restrict__ acc2Q,
                         const float* __restrict__ g2, const float* __restrict__ b2,
                         const float* __restrict__ xyz0, const float* __restrict__ xyz1,
                         int* __restrict__ knn1){
  if(blockIdx.x < BATCH*NS0)
    pass1_body<64,NPTS,1>(blockIdx.x, t2, nullptr, knn0, fps0, wt0, hmax0, hmin0, part0, NS0,
                          acc2S, acc2Q, g2, b2);
  else
    knn_body<NS0>(blockIdx.x-BATCH*NS0, xyz0, xyz1, NS1, knn1);
}

// L7: pass1b MODE2 — gathers from hmax0/hmin0 with stage-0 BN+ReLU fused (no f1)
__global__ __launch_bounds__(128, 2) void k_pass1b(const float* __restrict__ hmax0,
                         const float* __restrict__ hmin0,
                         const int* __restrict__ knn1, const int* __restrict__ fps1,
                         const float* __restrict__ wt1,
                         float* __restrict__ hmax1, float* __restrict__ hmin1, float* __restrict__ part1,
                         const float* __restrict__ accB0S, const float* __restrict__ accB0Q,
                         const float* __restrict__ gsg0, const float* __restrict__ bsg0){
  pass1_body<128,NS0,2>(blockIdx.x, hmax0, hmin0, knn1, fps1, wt1, hmax1, hmin1, part1, NS1,
                        accB0S, accB0Q, gsg0, bsg0);
}

// row-coalesced partial-sum reduce: block = 64 rows; one atomic per column
__global__ __launch_bounds__(256) void k_statsB(const float* __restrict__ part, int W,
                                                float* __restrict__ acc){
  int tid = threadIdx.x;
  int r0 = blockIdx.x*64;
  for(int c=tid; c<W; c+=256){
    float a=0.f;
    for(int r=0;r<64;r++) a += part[(size_t)(r0+r)*W + c];
    atomicAdd(acc+c, a);
  }
}

// stage-1 postmax + transpose via LDS tile; combines the doubled stat rows.
__global__ __launch_bounds__(256) void k_post1tr(const float* __restrict__ hmax, const float* __restrict__ hmin,
        const float* __restrict__ aS, const float* __restrict__ aQ,
        const float* __restrict__ g, const float* __restrict__ bb, float* __restrict__ out){
  __shared__ float ssc[64], ssh[64];
  __shared__ float tile[64][129];
  int tid = threadIdx.x;
  int blk = blockIdx.x; int b = blk>>2; int c0 = (blk&3)*64;
  if(tid<64){
    int o = c0+tid;
    float m = aS[o]/M1F, v = aQ[o]/M1F - m*m; if(v<0.f) v=0.f;
    float sc = rsqrtf(v+EPSV)*g[o];
    ssc[tid]=sc; ssh[tid]=bb[o]-m*sc;
  }
  __syncthreads();
  for(int i=tid; i<128*64; i+=256){
    int r=i>>6, ch=i&63;
    size_t rb = (size_t)(b*NS1+r)*2;
    float sc = ssc[ch];
    float va = hmax[rb*256 + c0+ch], vb = hmax[(rb+1)*256 + c0+ch];
    float wa = hmin[rb*256 + c0+ch], wb = hmin[(rb+1)*256 + c0+ch];
    float h = (sc>=0.f) ? fmaxf(va,vb) : fminf(wa,wb);
    float v = h*sc + ssh[ch];
    tile[ch][r] = v>0.f ? v : 0.f;
  }
  __syncthreads();
  for(int i=tid; i<64*128; i+=256){
    int ch=i>>7, s=i&127;
    out[(size_t)b*(256*NS1) + (size_t)(c0+ch)*NS1 + s] = tile[ch][s];
  }
}

extern "C" void kernel_launch(void* const* d_in, const int* in_sizes, int n_in,
                              void* d_out, int out_size, void* d_ws, size_t ws_size,
                              hipStream_t stream){
  const float* x    = (const float*)d_in[0];
  const float* w1   = (const float*)d_in[1];
  const float* g1   = (const float*)d_in[2];
  const float* b1   = (const float*)d_in[3];
  const float* w2   = (const float*)d_in[4];
  const float* g2   = (const float*)d_in[5];
  const float* b2   = (const float*)d_in[6];
  const float* wsg0 = (const float*)d_in[7];
  const float* gsg0 = (const float*)d_in[8];
  const float* bsg0 = (const float*)d_in[9];
  const float* wsg1 = (const float*)d_in[10];
  const float* gsg1 = (const float*)d_in[11];
  const float* bsg1 = (const float*)d_in[12];
  float* out = (float*)d_out;

  float* wsf = (float*)d_ws;
  float* coords = wsf;                    wsf += BATCH*NPTS*3;
  float* t1     = wsf;                    wsf += BATCH*NPTS*64;   // ALIASED: part1 after L3
  float* t2     = wsf;                    wsf += BATCH*NPTS*64;   // ALIASED: hmax1|hmin1 after L5
  float* acc1S=wsf; wsf+=64;  float* acc1Q=wsf; wsf+=64;          // contiguous 1024-float accum block
  float* acc2S=wsf; wsf+=64;  float* acc2Q=wsf; wsf+=64;
  float* accB0=wsf; wsf+=256;                                      // [S x128][Q x128]
  float* accB1=wsf; wsf+=512;                                      // [S x256][Q x256]
  int*   fps0 = (int*)wsf;                wsf += BATCH*NS0;
  float* xyz0 = wsf;                      wsf += BATCH*NS0*3;
  int*   knn0 = (int*)wsf;                wsf += BATCH*NS0*KK;
  float* hmax0= wsf;                      wsf += BATCH*NS0*128;
  float* hmin0= wsf;                      wsf += BATCH*NS0*128;
  float* part0= wsf;                      wsf += BATCH*NS0*2*128;
  int*   fps1 = (int*)wsf;                wsf += BATCH*NS1;
  float* xyz1 = wsf;                      wsf += BATCH*NS1*3;
  int*   knn1 = (int*)wsf;                wsf += BATCH*NS1*KK;
  float* wt0  = wsf;                      wsf += 128*128;
  float* wt1  = wsf;                      wsf += 256*256;
  // aliases (t1 dead after L3; t2 dead after L5)
  float* part1 = t1;                      // (NB1*2) x 512 floats == |t1|
  float* hmax1 = t2;                      // (NB1*2) x 256
  float* hmin1 = t2 + BATCH*NS1*2*256;

  const int DYN_L3 = (NPTS*3 + NS0)*4 + 2*4*8;     // fps0 union (>= embed2 17408)
  const int DYN_L4 = NS0*16 + NS1*4;               // fps1 float4 sp + sidx = 4608

  // L1: embed1 || weight transposes || zero accumulators (no memset op)
  k_embed1_wt<<<dim3(833), dim3(256), 0, stream>>>(x, w1, coords, t1, wsg0, wt0, wsg1, wt1, acc1S);
  // L2: BN1 stats
  k_statsA<<<dim3(256), dim3(64), 0, stream>>>(t1, acc1S, acc1Q);
  // L3: fps0 (FROZEN v4) || embed2 + fused BN2 stats
  k_fps0_embed2<<<dim3(BATCH+512), dim3(256), DYN_L3, stream>>>(x, fps0, xyz0,
                                                  t1, w2, acc1S, acc1Q, g1, b1, t2, acc2S, acc2Q);
  // L4: fps1 || knn0 (top-2 tournament)
  k_fps1_knn0<<<dim3(BATCH + BATCH*NS0), dim3(64), DYN_L4, stream>>>(xyz0, fps1, xyz1, coords, knn0);
  // L5: pass1a (BN2 fused) || knn1 (top-2 tournament)
  k_pass1a_knn1<<<dim3(BATCH*NS0 + BATCH*NS1), dim3(64), 0, stream>>>(t2, knn0, fps0, wt0,
                                                  hmax0, hmin0, part0,
                                                  acc2S, acc2Q, g2, b2,
                                                  xyz0, xyz1, knn1);
  // L6: reduce part0 -> accB0
  k_statsB<<<dim3(64), dim3(256), 0, stream>>>(part0, 256, accB0);
  // L7: pass1b (BN0-select fused; f1 never materialized)
  k_pass1b<<<dim3(BATCH*NS1), dim3(128), 0, stream>>>(hmax0, hmin0, knn1, fps1, wt1,
                                                  hmax1, hmin1, part1,
                                                  accB0, accB0+128, gsg0, bsg0);
  // L8: reduce part1 -> accB1
  k_statsB<<<dim3(64), dim3(256), 0, stream>>>(part1, 512, accB1);
  // L9: postmax + transpose -> out
  k_post1tr<<<dim3(64), dim3(256), 0, stream>>>(hmax1, hmin1, accB1, accB1+256, gsg1, bsg1, out);
}

// Round 15
// 388.423 us; speedup vs baseline: 1.0715x; 1.0360x over previous
//
#include <hip/hip_runtime.h>
#include <float.h>

#define BATCH 16
#define NPTS  2048
#define NS0   256
#define NS1   128
#define KK    32
#define EPSV  1e-5f
#define MROWS 32768.0f   // BATCH*NPTS
#define M0F   131072.0f  // BATCH*NS0*KK
#define M1F   65536.0f   // BATCH*NS1*KK

// exact numpy-order squared distance: ((dx*dx + dy*dy) + dz*dz), no FMA contraction
__device__ __forceinline__ float sqdist(float ax,float ay,float az,float bx,float by,float bz){
  float dx=__fsub_rn(ax,bx), dy=__fsub_rn(ay,by), dz=__fsub_rn(az,bz);
  return __fadd_rn(__fadd_rn(__fmul_rn(dx,dx),__fmul_rn(dy,dy)),__fmul_rn(dz,dz));
}

// ---- native f32/u32 DPP ladders (cheap wave64 reduce; winner broadcast via readlane 63)
template<int CTRL,int RM>
__device__ __forceinline__ float dpp_fmax_s(float x){
  int t = __builtin_amdgcn_update_dpp((int)0xFF800000, __float_as_int(x), CTRL, RM, 0xf, false);
  return fmaxf(x, __int_as_float(t));
}
template<int CTRL,int RM>
__device__ __forceinline__ float dpp_fmin_s(float x){
  int t = __builtin_amdgcn_update_dpp(0x7F800000, __float_as_int(x), CTRL, RM, 0xf, false);
  return fminf(x, __int_as_float(t));
}
template<int CTRL,int RM>
__device__ __forceinline__ unsigned dpp_umin_s(unsigned x){
  unsigned t = (unsigned)__builtin_amdgcn_update_dpp(-1, (int)x, CTRL, RM, 0xf, false);
  return t<x ? t : x;
}
// argmax over (v,idx): max value, tie -> lowest idx (matches np.argmax first-occurrence)
__device__ __forceinline__ void wave_argmax_f32(float v, unsigned idx, float& mall, int& sel){
  float m=v;
  m=dpp_fmax_s<0x111,0xf>(m); m=dpp_fmax_s<0x112,0xf>(m); m=dpp_fmax_s<0x114,0xf>(m);
  m=dpp_fmax_s<0x118,0xf>(m); m=dpp_fmax_s<0x142,0xa>(m); m=dpp_fmax_s<0x143,0xc>(m);
  mall = __int_as_float(__builtin_amdgcn_readlane(__float_as_int(m),63));
  unsigned c = (v==mall)? idx : 0xFFFFFFFFu;
  c=dpp_umin_s<0x111,0xf>(c); c=dpp_umin_s<0x112,0xf>(c); c=dpp_umin_s<0x114,0xf>(c);
  c=dpp_umin_s<0x118,0xf>(c); c=dpp_umin_s<0x142,0xa>(c); c=dpp_umin_s<0x143,0xc>(c);
  sel = (int)(unsigned)__builtin_amdgcn_readlane((int)c,63);
}
// argmin over (v,idx): min value, tie -> lowest idx (matches stable top_k)
__device__ __forceinline__ int wave_argmin_f32(float v, unsigned idx){
  float m=v;
  m=dpp_fmin_s<0x111,0xf>(m); m=dpp_fmin_s<0x112,0xf>(m); m=dpp_fmin_s<0x114,0xf>(m);
  m=dpp_fmin_s<0x118,0xf>(m); m=dpp_fmin_s<0x142,0xa>(m); m=dpp_fmin_s<0x143,0xc>(m);
  float mall = __int_as_float(__builtin_amdgcn_readlane(__float_as_int(m),63));
  unsigned c = (v==mall)? idx : 0xFFFFFFFFu;
  c=dpp_umin_s<0x111,0xf>(c); c=dpp_umin_s<0x112,0xf>(c); c=dpp_umin_s<0x114,0xf>(c);
  c=dpp_umin_s<0x118,0xf>(c); c=dpp_umin_s<0x142,0xa>(c); c=dpp_umin_s<0x143,0xc>(c);
  return (int)(unsigned)__builtin_amdgcn_readlane((int)c,63);
}

// ================= device bodies =================

// embed1 v2 (r12-proven): 64 points/block, LDS-staged coalesced t1 writes.
__device__ void embed1_body(int bid, const float* __restrict__ x, const float* __restrict__ w1,
                            float* __restrict__ coords, float* __restrict__ t1){
  __shared__ float w[192];
  __shared__ float xs[3][64];
  __shared__ float fin[64][65];
  int tid = threadIdx.x;
  if (tid < 192) w[tid] = w1[tid];
  int base = bid*64;
  int b = base / NPTS, n0 = base % NPTS;
  if (tid < 192){
    int ch = tid>>6, i = tid&63;
    xs[ch][i] = x[((size_t)b*3+ch)*NPTS + n0 + i];
  }
  __syncthreads();
  if (tid < 64){
    coords[(size_t)(base+tid)*3+0]=xs[0][tid];
    coords[(size_t)(base+tid)*3+1]=xs[1][tid];
    coords[(size_t)(base+tid)*3+2]=xs[2][tid];
  }
  int p = tid>>2, c0 = (tid&3)<<4;
  float cx=xs[0][p], cy=xs[1][p], cz=xs[2][p];
  #pragma unroll
  for(int j=0;j<16;j++){
    int c = c0+j;
    fin[p][c] = cx*w[c*3+0] + cy*w[c*3+1] + cz*w[c*3+2];
  }
  __syncthreads();
  for(int i=tid;i<4096;i+=256){
    int pp=i>>6, c=i&63;
    t1[(size_t)base*64 + i] = fin[pp][c];
  }
}

__device__ void wt_body(int gid, const float* __restrict__ w0, float* __restrict__ wt0,
                        const float* __restrict__ w1, float* __restrict__ wt1){
  if(gid < 128*128){
    int o = gid % 128, c = gid / 128;
    wt0[gid] = w0[o*128 + c];
  } else {
    int g2 = gid - 128*128;
    if(g2 >= 256*256) return;
    int o = g2 % 256, c = g2 / 256;
    wt1[g2] = w1[o*256 + c];
  }
}

// coalesced per-block channel sums + one atomic per channel per block (64 thr)
__device__ void statsA_body(int blk, const float* __restrict__ t,
                            float* __restrict__ accS, float* __restrict__ accQ){
  int c = threadIdx.x;
  int r0 = blk*128;
  float s=0.f, q=0.f;
  for(int r=0;r<128;r++){
    float v = t[(size_t)(r0+r)*64 + c];
    s+=v; q+=v*v;
  }
  atomicAdd(accS+c, s);
  atomicAdd(accQ+c, q);
}

// embed2 + fused BN2 stats (hidden under fps0 — free)
__device__ void embed2_body(int bid, const float* __restrict__ t1, const float* __restrict__ w2,
                            const float* __restrict__ accS, const float* __restrict__ accQ,
                            const float* __restrict__ g1, const float* __restrict__ b1,
                            float* __restrict__ t2,
                            float* __restrict__ acc2S, float* __restrict__ acc2Q,
                            float* ls, float* lq, char* smem){
  float (*fin)[64] = (float(*)[64])smem;
  float* sm = (float*)smem + 4096;
  float* sr = sm+64; float* sg = sr+64; float* sb = sg+64;
  int tid = threadIdx.x;
  if (tid<64){
    float S=accS[tid], Q=accQ[tid];
    float m = S/MROWS, v = Q/MROWS - m*m; if(v<0.f) v=0.f;
    sm[tid]=m; sr[tid]=rsqrtf(v+EPSV); sg[tid]=g1[tid]; sb[tid]=b1[tid];
    ls[tid]=0.f; lq[tid]=0.f;
  }
  __syncthreads();
  int base = bid*64;
  for(int i=tid;i<4096;i+=256){
    int p=i>>6, c=i&63;
    float v = t1[(size_t)(base+p)*64 + c];
    v = (v - sm[c])*sr[c]*sg[c] + sb[c];
    fin[p][c] = v>0.f ? v : 0.f;
  }
  __syncthreads();
  int o = tid & 63, p0 = tid>>6;
  float acc[16];
  #pragma unroll
  for(int i=0;i<16;i++) acc[i]=0.f;
  for(int cc=0; cc<64; cc+=4){
    float4 wv = *(const float4*)(w2 + o*64 + cc);
    #pragma unroll
    for(int i=0;i<16;i++){
      float4 f4 = *(const float4*)&fin[p0 + i*4][cc];
      acc[i] += f4.x*wv.x + f4.y*wv.y + f4.z*wv.z + f4.w*wv.w;
    }
  }
  float s=0.f,q=0.f;
  #pragma unroll
  for(int i=0;i<16;i++){
    float v = acc[i];
    t2[(size_t)(base+p0+i*4)*64 + o] = v;
    s+=v; q+=v*v;
  }
  atomicAdd(&ls[o], s);
  atomicAdd(&lq[o], q);
  __syncthreads();
  if(tid<64){ atomicAdd(acc2S+tid, ls[tid]); atomicAdd(acc2Q+tid, lq[tid]); }
}

// multi-wave FPS v4 (FROZEN: measured 124-127us). Do not restructure.
template<int P, int S, int T>
__device__ void fps_body(int b, const float* __restrict__ x, int* __restrict__ outIdx,
                         float* __restrict__ outXyz, char* smem){
  constexpr int PPT = P/T;
  constexpr int NW  = T/64;
  float* sx=(float*)smem; float* sy=sx+P; float* sz=sy+P;
  int* sidx=(int*)(sz+P);
  unsigned long long* rv64=(unsigned long long*)(sidx+S);
  int tid = threadIdx.x;
  const float* xb = x + (size_t)b*3*P;
  float px[PPT], py[PPT], pz[PPT], dist[PPT];
  #pragma unroll
  for(int i=0;i<PPT;i++){
    int n = i*T + tid;
    float X=xb[n], Y=xb[P+n], Z=xb[2*P+n];
    px[i]=X; py[i]=Y; pz[i]=Z; dist[i]=1e10f;
    sx[n]=X; sy[n]=Y; sz[n]=Z;
  }
  __syncthreads();
  int cur = 0;
  float cx=sx[0], cy=sy[0], cz=sz[0];
  for(int s=0;s<S;s++){
    if(tid==0) sidx[s]=cur;
    if(s==S-1) break;
    float bv=-FLT_MAX; int bi=0;
    #pragma unroll
    for(int i=0;i<PPT;i++){
      float d = sqdist(px[i],py[i],pz[i],cx,cy,cz);
      float nd = fminf(dist[i], d);
      dist[i]=nd;
      int n = i*T + tid;
      if(nd>bv){ bv=nd; bi=n; }
    }
    float mall; int sel;
    wave_argmax_f32(bv,(unsigned)bi,mall,sel);
    int sl = s & 1;
    if((tid&63)==0) rv64[sl*NW+(tid>>6)] = ((unsigned long long)__float_as_uint(mall)<<32)|(unsigned)(~sel);
    __syncthreads();
    unsigned long long wk = rv64[sl*NW];
    #pragma unroll
    for(int w=1;w<NW;w++){ unsigned long long t = rv64[sl*NW+w]; if(t>wk) wk=t; }
    cur = (int)(~(unsigned)wk);
    cx=sx[cur]; cy=sy[cur]; cz=sz[cur];
  }
  __syncthreads();
  for(int i=tid; i<S; i+=T){
    int id = sidx[i];
    outIdx[b*S+i] = id;
    outXyz[((size_t)b*S+i)*3+0] = sx[id];
    outXyz[((size_t)b*S+i)*3+1] = sy[id];
    outXyz[((size_t)b*S+i)*3+2] = sz[id];
  }
}

// single-wave FPS; float4-packed LDS points
template<int P, int S>
__device__ void fps_wave_body(int b, const float* __restrict__ pts, int* __restrict__ outIdx,
                              float* __restrict__ outXyz, char* smem){
  constexpr int PPT = P/64;
  float4* sp = (float4*)smem;
  int* sidx = (int*)(smem + P*sizeof(float4));
  int lane = threadIdx.x;
  const float* p = pts + (size_t)b*P*3;
  float px[PPT], py[PPT], pz[PPT], dist[PPT];
  #pragma unroll
  for(int i=0;i<PPT;i++){
    int n = i*64 + lane;
    float X=p[n*3], Y=p[n*3+1], Z=p[n*3+2];
    px[i]=X; py[i]=Y; pz[i]=Z; dist[i]=1e10f;
    sp[n] = make_float4(X,Y,Z,0.f);
  }
  __syncthreads();
  int cur = 0;
  float cx=sp[0].x, cy=sp[0].y, cz=sp[0].z;
  for(int s=0;s<S;s++){
    if(lane==0) sidx[s]=cur;
    if(s==S-1) break;
    float bv=-FLT_MAX; int bi=0;
    #pragma unroll
    for(int i=0;i<PPT;i++){
      float d = sqdist(px[i],py[i],pz[i],cx,cy,cz);
      float nd = fminf(dist[i], d);
      dist[i]=nd;
      int n = i*64 + lane;
      if(nd>bv){ bv=nd; bi=n; }
    }
    float mall; int sel;
    wave_argmax_f32(bv,(unsigned)bi,mall,sel);
    cur = sel;
    float4 cp = sp[cur];
    cx=cp.x; cy=cp.y; cz=cp.z;
  }
  __syncthreads();
  for(int i=lane; i<S; i+=64){
    int id = sidx[i];
    float4 cp = sp[id];
    outIdx[b*S+i] = id;
    outXyz[((size_t)b*S+i)*3+0] = cp.x;
    outXyz[((size_t)b*S+i)*3+1] = cp.y;
    outXyz[((size_t)b*S+i)*3+2] = cp.z;
  }
}

// KNN tournament v2 (r14-proven): per-lane top-2 cache + consumed bitmask, one wave.
// outRow: 32 ints (LDS). Selection bit-identical to full rescan.
template<int P>
__device__ void knn_compute(const float* __restrict__ p, float qx, float qy, float qz,
                            int* outRow){
  constexpr int E = P/64;
  int lane = threadIdx.x & 63;
  float dl[E];
  float b1=FLT_MAX, b2=FLT_MAX;
  unsigned i1=0xFFFFFFFFu, i2=0xFFFFFFFFu, consumed=0u;
  #pragma unroll
  for(int i=0;i<E;i++){
    unsigned n = i*64 + lane;
    float v = sqdist(qx,qy,qz,p[n*3],p[n*3+1],p[n*3+2]);
    dl[i] = v;
    bool lt1 = v<b1, lt2 = v<b2;
    float    nb2 = lt1 ? b1 : (lt2 ? v : b2);
    unsigned ni2 = lt1 ? i1 : (lt2 ? n : i2);
    b1 = lt1 ? v : b1; i1 = lt1 ? n : i1;
    b2 = nb2; i2 = ni2;
  }
  for(int j=0;j<KK;j++){
    int sel = wave_argmin_f32(b1, i1);
    if(lane==0) outRow[j] = sel;
    if((sel & 63) == lane){
      consumed |= 1u << (sel >> 6);
      b1 = b2; i1 = i2;
      b2 = FLT_MAX; i2 = 0xFFFFFFFFu;
      if(b1 == FLT_MAX){
        #pragma unroll
        for(int i=0;i<E;i++){
          float v = ((consumed>>i)&1u) ? FLT_MAX : dl[i];
          unsigned n = i*64 + lane;
          bool lt1 = v<b1, lt2 = v<b2;
          float    nb2 = lt1 ? b1 : (lt2 ? v : b2);
          unsigned ni2 = lt1 ? i1 : (lt2 ? n : i2);
          b1 = lt1 ? v : b1; i1 = lt1 ? n : i1;
          b2 = nb2; i2 = ni2;
        }
      }
    }
  }
}

// register-tiled outer-product GEMM with fused input transform; smem carved by caller.
// MODE 1: BN+ReLU from raw sums (pass1a, feats=t2).
// MODE 2: BN-select+ReLU over (hmax0,hmin0) (pass1b) — f1 never materialized.
// knnrow: 32 ints (LDS). ci: center index within batch.
template<int C, int P, int MODE>
__device__ void pass1_body(int bq, const float* __restrict__ feats, const float* __restrict__ feats2,
                           const int* knnrow, int ci, const float* __restrict__ WT,
                           float* __restrict__ hmax, float* __restrict__ hmin,
                           float* __restrict__ part, int S,
                           const float* __restrict__ accS, const float* __restrict__ accQ,
                           const float* __restrict__ bg, const float* __restrict__ bb,
                           char* smem){
  constexpr int O   = 2*C;
  constexpr int TPB = C;
  constexpr int C4  = C/4;
  constexpr int OG  = O/8;
  constexpr int LDC = C+4;
  float* gfp = (float*)smem;            // KK*LDC
  float* cf  = gfp + KK*LDC;            // C
  float* sa  = cf + C;                  // C
  float* sbb = sa + C;                  // C
  float* sct = sbb + C;                 // O
  int tid = threadIdx.x;
  int b = bq / S;
  const float* fb = feats + (size_t)b*P*C;
  const float* fb2 = (MODE==2) ? feats2 + (size_t)b*P*C : nullptr;
  {
    float Mv = (MODE==1) ? MROWS : M0F;
    float S_=accS[tid], Q_=accQ[tid];
    float m = S_/Mv, vv = Q_/Mv - m*m; if(vv<0.f) vv=0.f;
    float a = rsqrtf(vv+EPSV)*bg[tid];
    float sh = bb[tid] - m*a;
    sa[tid]=a; sbb[tid]=sh;
    float raw;
    if(MODE==1) raw = fb[(size_t)ci*C + tid];
    else        raw = (a>=0.f) ? fb[(size_t)ci*C + tid] : fb2[(size_t)ci*C + tid];
    float cv = a*raw + sh;
    cf[tid] = cv>0.f ? cv : 0.f;
  }
  __syncthreads();
  for(int i=tid; i<KK*C4; i+=TPB){
    int k = i/C4, d4 = i - k*C4;
    size_t row = (size_t)knnrow[k]*C;
    float4 a4 = *(const float4*)&sa[d4*4];
    float4 s4 = *(const float4*)&sbb[d4*4];
    float4 c4 = *(const float4*)&cf[d4*4];
    float4 g  = ((const float4*)(fb + row))[d4];
    float4 r;
    if(MODE==2){
      float4 g2 = ((const float4*)(fb2 + row))[d4];
      float gx = (a4.x>=0.f? g.x : g2.x)*a4.x + s4.x; gx = gx>0.f?gx:0.f;
      float gy = (a4.y>=0.f? g.y : g2.y)*a4.y + s4.y; gy = gy>0.f?gy:0.f;
      float gz = (a4.z>=0.f? g.z : g2.z)*a4.z + s4.z; gz = gz>0.f?gz:0.f;
      float gw = (a4.w>=0.f? g.w : g2.w)*a4.w + s4.w; gw = gw>0.f?gw:0.f;
      r.x=gx-c4.x; r.y=gy-c4.y; r.z=gz-c4.z; r.w=gw-c4.w;
    } else {
      float gx = a4.x*g.x+s4.x; gx = gx>0.f?gx:0.f;
      float gy = a4.y*g.y+s4.y; gy = gy>0.f?gy:0.f;
      float gz = a4.z*g.z+s4.z; gz = gz>0.f?gz:0.f;
      float gw = a4.w*g.w+s4.w; gw = gw>0.f?gw:0.f;
      r.x=gx-c4.x; r.y=gy-c4.y; r.z=gz-c4.z; r.w=gw-c4.w;
    }
    *(float4*)&gfp[k*LDC + d4*4] = r;
  }
  __syncthreads();
  {
    int o2 = tid*2;
    float ct0=0.f, ct1=0.f;
    for(int c=0;c<C;c+=4){
      float4 c4 = *(const float4*)&cf[c];
      #pragma unroll
      for(int t=0;t<4;t++){
        float cv = ((const float*)&c4)[t];
        float2 wh = *(const float2*)&WT[(size_t)(C+c+t)*O + o2];
        ct0 += cv*wh.x; ct1 += cv*wh.y;
      }
    }
    sct[o2]=ct0; sct[o2+1]=ct1;
  }
  __syncthreads();
  int kg = tid / OG;
  int og = tid % OG;
  float acc[8][8];
  #pragma unroll
  for(int a=0;a<8;a++)
    #pragma unroll
    for(int bb2=0;bb2<8;bb2++) acc[a][bb2]=0.f;
  for(int dc=0; dc<C4; dc++){
    float4 g4[8];
    #pragma unroll
    for(int jk=0;jk<8;jk++) g4[jk] = *(const float4*)&gfp[(kg*8+jk)*LDC + dc*4];
    #pragma unroll
    for(int t=0;t<4;t++){
      const float* wrow = WT + (size_t)(dc*4+t)*O + og*8;
      float4 wa = *(const float4*)wrow;
      float4 wb = *(const float4*)(wrow+4);
      #pragma unroll
      for(int jk=0;jk<8;jk++){
        float gs = ((const float*)&g4[jk])[t];
        acc[jk][0] += gs*wa.x; acc[jk][1] += gs*wa.y; acc[jk][2] += gs*wa.z; acc[jk][3] += gs*wa.w;
        acc[jk][4] += gs*wb.x; acc[jk][5] += gs*wb.y; acc[jk][6] += gs*wb.z; acc[jk][7] += gs*wb.w;
      }
    }
  }
  float tmx[8],tmn[8],tsm[8],tsq[8];
  #pragma unroll
  for(int jo=0;jo<8;jo++){
    int o = og*8+jo;
    float ct = sct[o];
    float s=0.f,q=0.f,mx=-FLT_MAX,mn=FLT_MAX;
    #pragma unroll
    for(int jk=0;jk<8;jk++){
      float h = acc[jk][jo] + ct;
      s+=h; q+=h*h; mx=fmaxf(mx,h); mn=fminf(mn,h);
    }
    tmx[jo]=mx; tmn[jo]=mn; tsm[jo]=s; tsq[jo]=q;
  }
  if constexpr (TPB==64){
    #pragma unroll
    for(int jo=0;jo<8;jo++){
      tmx[jo]=fmaxf(tmx[jo],__shfl_xor(tmx[jo],16)); tmx[jo]=fmaxf(tmx[jo],__shfl_xor(tmx[jo],32));
      tmn[jo]=fminf(tmn[jo],__shfl_xor(tmn[jo],16)); tmn[jo]=fminf(tmn[jo],__shfl_xor(tmn[jo],32));
      tsm[jo]+=__shfl_xor(tsm[jo],16); tsm[jo]+=__shfl_xor(tsm[jo],32);
      tsq[jo]+=__shfl_xor(tsq[jo],16); tsq[jo]+=__shfl_xor(tsq[jo],32);
    }
    if(tid<OG){
      #pragma unroll
      for(int jo=0;jo<8;jo++){
        int o = tid*8+jo;
        hmax[(size_t)bq*O+o]=tmx[jo]; hmin[(size_t)bq*O+o]=tmn[jo];
        part[(size_t)bq*2*O+o]=tsm[jo]; part[(size_t)bq*2*O+O+o]=tsq[jo];
      }
    }
  } else {
    #pragma unroll
    for(int jo=0;jo<8;jo++){
      tmx[jo]=fmaxf(tmx[jo],__shfl_xor(tmx[jo],32));
      tmn[jo]=fminf(tmn[jo],__shfl_xor(tmn[jo],32));
      tsm[jo]+=__shfl_xor(tsm[jo],32);
      tsq[jo]+=__shfl_xor(tsq[jo],32);
    }
    int wv = tid>>6;
    if((tid&63)<32){
      int og_ = tid&31;
      size_t rb = (size_t)bq*2 + wv;        // doubled row per wave; combined downstream
      #pragma unroll
      for(int jo=0;jo<8;jo++){
        int o = og_*8+jo;
        hmax[rb*O+o]=tmx[jo]; hmin[rb*O+o]=tmn[jo];
        part[rb*2*O+o]=tsm[jo]; part[rb*2*O+O+o]=tsq[jo];
      }
    }
  }
}

// ================= kernels =================

// L1: embed1 (0..511) || wt (512..831) || zero 1024 accum floats (832)
__global__ __launch_bounds__(256) void k_embed1_wt(const float* __restrict__ x, const float* __restrict__ w1,
                         float* __restrict__ coords, float* __restrict__ t1,
                         const float* __restrict__ wsg0, float* __restrict__ wt0,
                         const float* __restrict__ wsg1, float* __restrict__ wt1,
                         float* __restrict__ accz){
  if(blockIdx.x < 512) embed1_body(blockIdx.x, x, w1, coords, t1);
  else if(blockIdx.x < 832) wt_body((blockIdx.x-512)*256 + threadIdx.x, wsg0, wt0, wsg1, wt1);
  else {
    int tid = threadIdx.x;
    accz[tid]=0.f; accz[tid+256]=0.f; accz[tid+512]=0.f; accz[tid+768]=0.f;
  }
}

// L2: BN1 stats (coalesced + atomic)
__global__ __launch_bounds__(64) void k_statsA(const float* __restrict__ t,
                         float* __restrict__ accS, float* __restrict__ accQ){
  statsA_body(blockIdx.x, t, accS, accQ);
}

// L3: fps0 (16 blocks) || embed2+stats2 (512 blocks); dyn smem = 25664 B (union)
__global__ __launch_bounds__(256, 1) void k_fps0_embed2(const float* __restrict__ x,
                         int* __restrict__ fps0, float* __restrict__ xyz0,
                         const float* __restrict__ t1, const float* __restrict__ w2,
                         const float* __restrict__ acc1S, const float* __restrict__ acc1Q,
                         const float* __restrict__ g1, const float* __restrict__ b1,
                         float* __restrict__ t2,
                         float* __restrict__ acc2S, float* __restrict__ acc2Q){
  extern __shared__ char smem[];
  __shared__ float ls[64], lq[64];
  if(blockIdx.x < BATCH) fps_body<NPTS,NS0,256>(blockIdx.x, x, fps0, xyz0, smem);
  else embed2_body(blockIdx.x-BATCH, t1, w2, acc1S, acc1Q, g1, b1, t2, acc2S, acc2Q, ls, lq, smem);
}

// L4: fps1 (blocks 0..15) || FUSED knn0+pass1a (blocks 16..4111). Static LDS union.
__global__ __launch_bounds__(64, 2) void k_fps1_p1a(const float* __restrict__ xyz0,
                         int* __restrict__ fps1, float* __restrict__ xyz1,
                         const float* __restrict__ coords, const float* __restrict__ t2,
                         const int* __restrict__ fps0, const float* __restrict__ wt0,
                         float* __restrict__ hmax0, float* __restrict__ hmin0, float* __restrict__ part0,
                         const float* __restrict__ acc2S, const float* __restrict__ acc2Q,
                         const float* __restrict__ g2, const float* __restrict__ b2){
  __shared__ __align__(16) char SU[10112];   // pass1a: 9984 + sknn 128; fps1 needs 4608
  if(blockIdx.x < BATCH){
    fps_wave_body<NS0,NS1>(blockIdx.x, xyz0, fps1, xyz1, SU);
    return;
  }
  int bq = blockIdx.x - BATCH;
  int b = bq / NS0;
  int* sknn = (int*)(SU + 9984);
  const float* pc = coords + (size_t)b*NPTS*3;
  float qx=xyz0[(size_t)bq*3], qy=xyz0[(size_t)bq*3+1], qz=xyz0[(size_t)bq*3+2];
  knn_compute<NPTS>(pc, qx, qy, qz, sknn);
  __syncthreads();
  pass1_body<64,NPTS,1>(bq, t2, nullptr, sknn, fps0[bq], wt0, hmax0, hmin0, part0, NS0,
                        acc2S, acc2Q, g2, b2, SU);
}

// L5: row-coalesced partial-sum reduce: block = 64 rows; one atomic per column
__global__ __launch_bounds__(256) void k_statsB(const float* __restrict__ part, int W,
                                                float* __restrict__ acc){
  int tid = threadIdx.x;
  int r0 = blockIdx.x*64;
  for(int c=tid; c<W; c+=256){
    float a=0.f;
    for(int r=0;r<64;r++) a += part[(size_t)(r0+r)*W + c];
    atomicAdd(acc+c, a);
  }
}

// L6: FUSED knn1+pass1b (2048 blocks x 128 thr): wave 0 computes the E=4 tournament,
// then both waves run the MODE2 GEMM (gathers hmax0/hmin0 with stage-0 BN fused).
__global__ __launch_bounds__(128, 2) void k_knn1_p1b(const float* __restrict__ xyz0,
                         const float* __restrict__ xyz1, const int* __restrict__ fps1,
                         const float* __restrict__ hmax0, const float* __restrict__ hmin0,
                         const float* __restrict__ wt1,
                         float* __restrict__ hmax1, float* __restrict__ hmin1, float* __restrict__ part1,
                         const float* __restrict__ accB0S, const float* __restrict__ accB0Q,
                         const float* __restrict__ gsg0, const float* __restrict__ bsg0){
  __shared__ __align__(16) char SU[19584];   // pass1b: 19456 + sknn 128
  int bq = blockIdx.x;
  int b = bq / NS1;
  int* sknn = (int*)(SU + 19456);
  if(threadIdx.x < 64){
    const float* pts = xyz0 + (size_t)b*NS0*3;
    float qx=xyz1[(size_t)bq*3], qy=xyz1[(size_t)bq*3+1], qz=xyz1[(size_t)bq*3+2];
    knn_compute<NS0>(pts, qx, qy, qz, sknn);
  }
  __syncthreads();
  pass1_body<128,NS0,2>(bq, hmax0, hmin0, sknn, fps1[bq], wt1, hmax1, hmin1, part1, NS1,
                        accB0S, accB0Q, gsg0, bsg0, SU);
}

// L8: stage-1 postmax + transpose via LDS tile; combines the doubled stat rows.
__global__ __launch_bounds__(256) void k_post1tr(const float* __restrict__ hmax, const float* __restrict__ hmin,
        const float* __restrict__ aS, const float* __restrict__ aQ,
        const float* __restrict__ g, const float* __restrict__ bb, float* __restrict__ out){
  __shared__ float ssc[64], ssh[64];
  __shared__ float tile[64][129];
  int tid = threadIdx.x;
  int blk = blockIdx.x; int b = blk>>2; int c0 = (blk&3)*64;
  if(tid<64){
    int o = c0+tid;
    float m = aS[o]/M1F, v = aQ[o]/M1F - m*m; if(v<0.f) v=0.f;
    float sc = rsqrtf(v+EPSV)*g[o];
    ssc[tid]=sc; ssh[tid]=bb[o]-m*sc;
  }
  __syncthreads();
  for(int i=tid; i<128*64; i+=256){
    int r=i>>6, ch=i&63;
    size_t rb = (size_t)(b*NS1+r)*2;
    float sc = ssc[ch];
    float va = hmax[rb*256 + c0+ch], vb = hmax[(rb+1)*256 + c0+ch];
    float wa = hmin[rb*256 + c0+ch], wb = hmin[(rb+1)*256 + c0+ch];
    float h = (sc>=0.f) ? fmaxf(va,vb) : fminf(wa,wb);
    float v = h*sc + ssh[ch];
    tile[ch][r] = v>0.f ? v : 0.f;
  }
  __syncthreads();
  for(int i=tid; i<64*128; i+=256){
    int ch=i>>7, s=i&127;
    out[(size_t)b*(256*NS1) + (size_t)(c0+ch)*NS1 + s] = tile[ch][s];
  }
}

extern "C" void kernel_launch(void* const* d_in, const int* in_sizes, int n_in,
                              void* d_out, int out_size, void* d_ws, size_t ws_size,
                              hipStream_t stream){
  const float* x    = (const float*)d_in[0];
  const float* w1   = (const float*)d_in[1];
  const float* g1   = (const float*)d_in[2];
  const float* b1   = (const float*)d_in[3];
  const float* w2   = (const float*)d_in[4];
  const float* g2   = (const float*)d_in[5];
  const float* b2   = (const float*)d_in[6];
  const float* wsg0 = (const float*)d_in[7];
  const float* gsg0 = (const float*)d_in[8];
  const float* bsg0 = (const float*)d_in[9];
  const float* wsg1 = (const float*)d_in[10];
  const float* gsg1 = (const float*)d_in[11];
  const float* bsg1 = (const float*)d_in[12];
  float* out = (float*)d_out;

  float* wsf = (float*)d_ws;
  float* coords = wsf;                    wsf += BATCH*NPTS*3;
  float* t1     = wsf;                    wsf += BATCH*NPTS*64;   // ALIASED: part1 after L3
  float* t2     = wsf;                    wsf += BATCH*NPTS*64;   // ALIASED: hmax1|hmin1 after L4
  float* acc1S=wsf; wsf+=64;  float* acc1Q=wsf; wsf+=64;          // contiguous 1024-float accum block
  float* acc2S=wsf; wsf+=64;  float* acc2Q=wsf; wsf+=64;
  float* accB0=wsf; wsf+=256;                                      // [S x128][Q x128]
  float* accB1=wsf; wsf+=512;                                      // [S x256][Q x256]
  int*   fps0 = (int*)wsf;                wsf += BATCH*NS0;
  float* xyz0 = wsf;                      wsf += BATCH*NS0*3;
  float* hmax0= wsf;                      wsf += BATCH*NS0*128;
  float* hmin0= wsf;                      wsf += BATCH*NS0*128;
  float* part0= wsf;                      wsf += BATCH*NS0*2*128;
  int*   fps1 = (int*)wsf;                wsf += BATCH*NS1;
  float* xyz1 = wsf;                      wsf += BATCH*NS1*3;
  float* wt0  = wsf;                      wsf += 128*128;
  float* wt1  = wsf;                      wsf += 256*256;
  // aliases (t1 dead after L3; t2 dead after L4)
  float* part1 = t1;                      // (NB1*2) x 512 floats == |t1|
  float* hmax1 = t2;                      // (NB1*2) x 256
  float* hmin1 = t2 + BATCH*NS1*2*256;

  const int DYN_L3 = (NPTS*3 + NS0)*4 + 2*4*8;     // fps0 union (>= embed2 17408)

  // L1: embed1 || weight transposes || zero accumulators
  k_embed1_wt<<<dim3(833), dim3(256), 0, stream>>>(x, w1, coords, t1, wsg0, wt0, wsg1, wt1, acc1S);
  // L2: BN1 stats
  k_statsA<<<dim3(256), dim3(64), 0, stream>>>(t1, acc1S, acc1Q);
  // L3: fps0 (FROZEN v4) || embed2 + fused BN2 stats
  k_fps0_embed2<<<dim3(BATCH+512), dim3(256), DYN_L3, stream>>>(x, fps0, xyz0,
                                                  t1, w2, acc1S, acc1Q, g1, b1, t2, acc2S, acc2Q);
  // L4: fps1 || fused knn0+pass1a
  k_fps1_p1a<<<dim3(BATCH + BATCH*NS0), dim3(64), 0, stream>>>(xyz0, fps1, xyz1,
                                                  coords, t2, fps0, wt0,
                                                  hmax0, hmin0, part0,
                                                  acc2S, acc2Q, g2, b2);
  // L5: reduce part0 -> accB0
  k_statsB<<<dim3(64), dim3(256), 0, stream>>>(part0, 256, accB0);
  // L6: fused knn1+pass1b (BN0-select fused; f1 never materialized)
  k_knn1_p1b<<<dim3(BATCH*NS1), dim3(128), 0, stream>>>(xyz0, xyz1, fps1,
                                                  hmax0, hmin0, wt1,
                                                  hmax1, hmin1, part1,
                                                  accB0, accB0+128, gsg0, bsg0);
  // L7: reduce part1 -> accB1
  k_statsB<<<dim3(64), dim3(256), 0, stream>>>(part1, 512, accB1);
  // L8: postmax + transpose -> out
  k_post1tr<<<dim3(64), dim3(256), 0, stream>>>(hmax1, hmin1, accB1, accB1+256, gsg1, bsg1, out);
}